// Round 1
// baseline (370.188 us; speedup 1.0000x reference)
//
#include <hip/hip_runtime.h>

typedef unsigned short u16;
typedef __attribute__((ext_vector_type(4))) float f32x4;
typedef __attribute__((ext_vector_type(8))) short s16x8;
typedef __attribute__((ext_vector_type(4))) unsigned short u16x4;

#define MFMA16(a, b, c) __builtin_amdgcn_mfma_f32_16x16x32_bf16((a), (b), (c), 0, 0, 0)

__device__ __forceinline__ u16 f2bf(float f) {
  union { float f; unsigned u; } v; v.f = f;
  unsigned u = v.u;
  u += 0x7fffu + ((u >> 16) & 1u);   // RNE
  return (u16)(u >> 16);
}

__device__ __forceinline__ void gl_lds16(const void* g, void* l) {
  __builtin_amdgcn_global_load_lds(
      (const __attribute__((address_space(1))) void*)g,
      (__attribute__((address_space(3))) void*)l, 16, 0, 0);
}

// ---------------- fused cast fp32 -> bf16 ----------------
__global__ void cast6(const float* __restrict__ x,
                      const float* __restrict__ w0, const float* __restrict__ w1,
                      const float* __restrict__ w2, const float* __restrict__ w3,
                      u16* __restrict__ ws) {
  const int y = blockIdx.y;
  const float* src;
  u16* dst;
  if (y < 2) { src = x + (size_t)y * 4194304; dst = ws + (size_t)y * 4194304; }
  else {
    src = (y == 2) ? w0 : (y == 3) ? w1 : (y == 4) ? w2 : w3;
    dst = ws + 8388608 + (size_t)(y - 2) * 4194304;
  }
  const int i = blockIdx.x * 256 + threadIdx.x;
  f32x4 v = ((const f32x4*)src)[i];
  u16x4 o;
#pragma unroll
  for (int e = 0; e < 4; ++e) o[e] = f2bf(v[e]);
  ((u16x4*)dst)[i] = o;
}

// ---------------- 128x128 GEMM core (kept for gemm_out) ----------------
template <int SWAP>
__device__ __forceinline__ void gemm_core(const u16* __restrict__ A,
                                          const u16* __restrict__ Bw,
                                          u16* sA, u16* sB,
                                          f32x4 (&acc)[4][4],
                                          int m0, int n0, int tid) {
  const int lane = tid & 63, w = tid >> 6;
  const int ln = lane & 15, quad = lane >> 4, ln7 = ln & 7;
  const int wm = (w >> 1) * 64, wn = (w & 1) * 64;
  const int srow = lane >> 3;
  const int scol = (((lane & 7) ^ srow)) * 8;

  for (int k0 = 0; k0 < 2048; k0 += 64) {
#pragma unroll
    for (int c = 0; c < 4; ++c) {
      const int chunk = c * 4 + w;
      const int row = chunk * 8 + srow;
      gl_lds16(A + (size_t)(m0 + row) * 2048 + k0 + scol, (char*)sA + chunk * 1024);
      gl_lds16(Bw + (size_t)(n0 + row) * 2048 + k0 + scol, (char*)sB + chunk * 1024);
    }
    __syncthreads();
#pragma unroll
    for (int kk = 0; kk < 64; kk += 32) {
      s16x8 af[4], bf[4];
      const int g = (kk >> 3) + quad;
#pragma unroll
      for (int t = 0; t < 4; ++t) {
        af[t] = *(const s16x8*)&sA[(wm + t * 16 + ln) * 64 + ((g ^ ln7) << 3)];
        bf[t] = *(const s16x8*)&sB[(wn + t * 16 + ln) * 64 + ((g ^ ln7) << 3)];
      }
#pragma unroll
      for (int tm = 0; tm < 4; ++tm)
#pragma unroll
        for (int tn = 0; tn < 4; ++tn)
          acc[tm][tn] = SWAP ? MFMA16(bf[tn], af[tm], acc[tm][tn])
                             : MFMA16(af[tm], bf[tn], acc[tm][tn]);
    }
    __syncthreads();
  }
}

// ---------------- 256x256 deep-pipelined GEMM core ----------------
// 4-slot LDS ring (4 x 32KB), BK=32, prefetch depth 3, counted vmcnt (T3+T4),
// setprio around MFMA cluster (T5). Staging pre-swizzles the global source
// column so frag ds_read_b128 is conflict-free (2 addrs / bank granule).
template <int SWAP>
__device__ __forceinline__ void gemm_core256(const u16* __restrict__ A,
                                             const u16* __restrict__ Bw,
                                             u16* smem,
                                             f32x4 (&acc)[8][4],
                                             int m0, int n0, int tid) {
  const int lane = tid & 63, w = tid >> 6;
  const int ln = lane & 15, quad = lane >> 4;
  const int wm = (w >> 2) << 7;                       // 0 / 128
  const int wn = (w & 3) << 6;                        // 0..192
  const int sr = tid >> 2;                            // staging row 0..127
  const int ssw = (((tid & 3) ^ ((sr >> 1) & 3)) << 3);  // swizzled src k-off
  const int swq = ((quad ^ ((ln >> 1) & 3)) << 3);       // swizzled frag k-off
  const int wofs = w << 9;                            // wave's LDS chunk (u16)

  const u16* Asrc = A + (size_t)(m0 + sr) * 2048 + ssw;
  const u16* Bsrc = Bw + (size_t)(n0 + sr) * 2048 + ssw;

  auto STAGE = [&](int t) {
    u16* sl = smem + ((t & 3) << 14);
    const int k0 = t << 5;
    gl_lds16(Asrc + k0,                sl + wofs);
    gl_lds16(Asrc + k0 + 128 * 2048,   sl + 4096 + wofs);
    gl_lds16(Bsrc + k0,                sl + 8192 + wofs);
    gl_lds16(Bsrc + k0 + 128 * 2048,   sl + 12288 + wofs);
  };

  auto COMPUTE = [&](int t) {
    const u16* sl = smem + ((t & 3) << 14);
    s16x8 af[8], bf[4];
#pragma unroll
    for (int j = 0; j < 4; ++j)
      bf[j] = *(const s16x8*)&sl[8192 + (wn + j * 16 + ln) * 32 + swq];
#pragma unroll
    for (int tt = 0; tt < 8; ++tt)
      af[tt] = *(const s16x8*)&sl[(wm + tt * 16 + ln) * 32 + swq];
    __builtin_amdgcn_s_setprio(1);
#pragma unroll
    for (int tt = 0; tt < 8; ++tt)
#pragma unroll
      for (int j = 0; j < 4; ++j)
        acc[tt][j] = SWAP ? MFMA16(bf[j], af[tt], acc[tt][j])
                          : MFMA16(af[tt], bf[j], acc[tt][j]);
    __builtin_amdgcn_s_setprio(0);
  };

  // prologue: fill 3 ring slots
  STAGE(0); STAGE(1); STAGE(2);

  // steady state: tile t needs its 4 loads landed; tiles t+1,t+2 (8 loads)
  // may stay in flight. lgkmcnt(0) seals this wave's ds_reads before the
  // raw barrier (slot (t+3)&3 is about to be overwritten).
#define STEP(T)                                                       \
  asm volatile("s_waitcnt vmcnt(8) lgkmcnt(0)" ::: "memory");         \
  __builtin_amdgcn_s_barrier();                                       \
  asm volatile("" ::: "memory");                                      \
  STAGE((T) + 3);                                                     \
  COMPUTE(T);

  int t = 0;
#pragma unroll 1
  for (int tb = 0; tb < 15; ++tb, t += 4) {
    STEP(t + 0)
    STEP(t + 1)
    STEP(t + 2)
    STEP(t + 3)
  }
  STEP(60)
#undef STEP

  // tail: tiles 61..63 (no more staging; shrink the allowed in-flight count)
  asm volatile("s_waitcnt vmcnt(8) lgkmcnt(0)" ::: "memory");
  __builtin_amdgcn_s_barrier();
  asm volatile("" ::: "memory");
  COMPUTE(61);
  asm volatile("s_waitcnt vmcnt(4) lgkmcnt(0)" ::: "memory");
  __builtin_amdgcn_s_barrier();
  asm volatile("" ::: "memory");
  COMPUTE(62);
  asm volatile("s_waitcnt vmcnt(0) lgkmcnt(0)" ::: "memory");
  __builtin_amdgcn_s_barrier();
  asm volatile("" ::: "memory");
  COMPUTE(63);
}

// ---------------- fused Q/K/V projection GEMMs (256^2 pipelined) ----------------
// z=0: Q -> [B,H,S,D] bf16 scaled 1/sqrt(D); z=1: K -> [B,H,S,D];
// z=2: V -> Vt [B,H,D,S] bf16 written directly.
__global__ __launch_bounds__(512, 2) void gemm_qkv256(
    const u16* __restrict__ A,
    const u16* __restrict__ W0, const u16* __restrict__ W1, const u16* __restrict__ W2,
    const float* __restrict__ b0, const float* __restrict__ b1, const float* __restrict__ b2,
    u16* __restrict__ Qo, u16* __restrict__ Ko, u16* __restrict__ Vo) {
  __shared__ __align__(16) u16 smem[65536];   // 128 KiB: 4 ring slots x (A 16K | B 16K)
  const int z = blockIdx.z;
  const u16* Bw = (z == 0) ? W0 : (z == 1) ? W1 : W2;
  const float* bias = (z == 0) ? b0 : (z == 1) ? b1 : b2;

  const int tid = threadIdx.x;
  const int lane = tid & 63, w = tid >> 6;
  const int ln = lane & 15, quad = lane >> 4;
  const int m0 = blockIdx.y * 256, n0 = blockIdx.x * 256;
  const int wm = (w >> 2) << 7, wn = (w & 3) << 6;

  f32x4 acc[8][4] = {};
  if (z < 2) {
    gemm_core256<1>(A, Bw, smem, acc, m0, n0, tid);
    u16* out = (z == 0) ? Qo : Ko;
    const float scale = (z == 0) ? 0.08838834764831845f : 1.0f;
#pragma unroll
    for (int tn = 0; tn < 4; ++tn) {
      const int n_base = n0 + wn + tn * 16 + quad * 4;
      const f32x4 bv = *(const f32x4*)&bias[n_base];
      const int h = n_base >> 7, dl = n_base & 127;
#pragma unroll
      for (int tm = 0; tm < 8; ++tm) {
        const int m = m0 + wm + tm * 16 + ln;
        const int b = m >> 11, s = m & 2047;
        u16x4 ov;
#pragma unroll
        for (int r = 0; r < 4; ++r) ov[r] = f2bf((acc[tm][tn][r] + bv[r]) * scale);
        *(u16x4*)&out[(((size_t)(b * 16 + h)) << 18) + ((size_t)s << 7) + dl] = ov;
      }
    }
  } else {
    gemm_core256<0>(A, Bw, smem, acc, m0, n0, tid);
    const int b = m0 >> 11;
#pragma unroll
    for (int tn = 0; tn < 4; ++tn) {
      const int n = n0 + wn + tn * 16 + ln;   // global d index
      const float bv = bias[n];
      const int h = n >> 7, dl = n & 127;
#pragma unroll
      for (int tm = 0; tm < 8; ++tm) {
        const int s_base = (m0 & 2047) + wm + tm * 16 + quad * 4;
        u16x4 ov;
#pragma unroll
        for (int r = 0; r < 4; ++r) ov[r] = f2bf(acc[tm][tn][r] + bv);
        *(u16x4*)&Vo[(((size_t)((b * 16 + h) * 128 + dl)) << 11) + s_base] = ov;
      }
    }
  }
}

// ---------------- output projection GEMM (fp32 out) ----------------
__global__ __launch_bounds__(256, 2) void gemm_out(const u16* __restrict__ A,
                                                   const u16* __restrict__ Bw,
                                                   const float* __restrict__ bias,
                                                   float* __restrict__ out) {
  __shared__ __align__(16) u16 smem[16384];
  u16* sA = smem;
  u16* sB = smem + 8192;
  const int tid = threadIdx.x;
  const int lane = tid & 63, w = tid >> 6;
  const int ln = lane & 15, quad = lane >> 4;
  const int m0 = blockIdx.y * 128, n0 = blockIdx.x * 128;
  const int wm = (w >> 1) * 64, wn = (w & 1) * 64;

  f32x4 acc[4][4] = {};
  gemm_core<1>(A, Bw, sA, sB, acc, m0, n0, tid);
#pragma unroll
  for (int tn = 0; tn < 4; ++tn) {
    const int n_base = n0 + wn + tn * 16 + quad * 4;
    const f32x4 bv = *(const f32x4*)&bias[n_base];
#pragma unroll
    for (int tm = 0; tm < 4; ++tm) {
      const int m = m0 + wm + tm * 16 + ln;
      f32x4 ov;
#pragma unroll
      for (int r = 0; r < 4; ++r) ov[r] = acc[tm][tn][r] + bv[r];
      *(f32x4*)&out[(size_t)m * 2048 + n_base] = ov;
    }
  }
}

// ---------------- causal flash attention (S^T orientation) ----------------
__global__ __launch_bounds__(256, 2) void attn_kernel(const u16* __restrict__ Q,
                                                      const u16* __restrict__ Kp,
                                                      const u16* __restrict__ Vt,
                                                      u16* __restrict__ ctx) {
  __shared__ __align__(16) u16 smem[24576];  // sP[8192] | sK[8192] | sV[8192]
  u16* sP = smem;
  u16* sK = smem + 8192;
  u16* sV = smem + 16384;

  const int flat = blockIdx.x + (blockIdx.y << 4);
  const int bh = flat >> 4;
  const int i = (flat < 256) ? (15 - (flat & 15)) : (flat & 15);  // pair work-balance
  const size_t base = (size_t)bh << 18;

  const int tid = threadIdx.x, lane = tid & 63, w = tid >> 6;
  const int ln = lane & 15, quad = lane >> 4, ln7 = lane & 7;

  // ---- stage Q tile (32KB) into sK..sV region, swizzled ----
#pragma unroll
  for (int c = 0; c < 8; ++c) {
    const int chunk0 = (c * 4 + w) * 64;
    const int chunk = chunk0 + lane;
    const int row = chunk >> 4, cc = chunk & 15;
    gl_lds16(Q + base + (size_t)((i * 128 + row) * 128 + ((cc ^ (row & 15)) << 3)),
             (char*)sK + chunk0 * 16);
  }
  __syncthreads();
  s16x8 qf[2][4];
#pragma unroll
  for (int qt = 0; qt < 2; ++qt)
#pragma unroll
    for (int kc = 0; kc < 4; ++kc)
      qf[qt][kc] =
          *(const s16x8*)&sK[(w * 32 + qt * 16 + ln) * 128 + (((kc * 4 + quad) ^ ln) << 3)];
  __syncthreads();

  auto stageK = [&](int j) {
#pragma unroll
    for (int c = 0; c < 4; ++c) {
      const int chunk0 = (c * 4 + w) * 64;
      const int chunk = chunk0 + lane;
      const int row = chunk >> 4, cc = chunk & 15;
      gl_lds16(Kp + base + (size_t)((j * 64 + row) * 128 + ((cc ^ (row & 15)) << 3)),
               (char*)sK + chunk0 * 16);
    }
  };
  auto stageV = [&](int j) {
#pragma unroll
    for (int c = 0; c < 4; ++c) {
      const int chunk0 = (c * 4 + w) * 64;
      const int chunk = chunk0 + lane;
      const int row = chunk >> 3, cc = chunk & 7;
      gl_lds16(Vt + base + (size_t)(row * 2048 + j * 64 + ((cc ^ (row & 7)) << 3)),
               (char*)sV + chunk0 * 16);
    }
  };

  stageK(0);
  stageV(0);
  __syncthreads();

  f32x4 o_acc[8][2] = {};
  float lsum[2] = {0.f, 0.f};
  const int jmax = 2 * i + 1;
  const int qg = i * 128 + w * 32 + ln;  // + qt*16 gives lane's global q

  for (int j = 0; j <= jmax; ++j) {
    // ---- S^T = K . Q^T (64k x 128q): A = K frags, B = Q regs ----
    f32x4 sacc[4][2] = {};
#pragma unroll
    for (int kc = 0; kc < 4; ++kc) {
      s16x8 kf[4];
#pragma unroll
      for (int kt = 0; kt < 4; ++kt)
        kf[kt] = *(const s16x8*)&sK[(kt * 16 + ln) * 128 + (((kc * 4 + quad) ^ ln) << 3)];
#pragma unroll
      for (int kt = 0; kt < 4; ++kt)
#pragma unroll
        for (int qt = 0; qt < 2; ++qt)
          sacc[kt][qt] = MFMA16(kf[kt], qf[qt][kc], sacc[kt][qt]);
    }

    // ---- exp + mask + pack P[q][k] via b64 writes (swizzle key q&14) ----
    const bool diag = (j >= 2 * i);
#pragma unroll
    for (int kt = 0; kt < 4; ++kt)
#pragma unroll
      for (int qt = 0; qt < 2; ++qt) {
        u16x4 pk;
#pragma unroll
        for (int r = 0; r < 4; ++r) {
          const int kg = j * 64 + kt * 16 + quad * 4 + r;
          float pv = __expf(sacc[kt][qt][r]);
          if (diag && kg > qg + qt * 16) pv = 0.f;
          lsum[qt] += pv;
          pk[r] = f2bf(pv);
        }
        const int qrow = w * 32 + qt * 16 + ln;
        const int c = kt * 4 + quad;
        *(u16x4*)&sP[qrow * 64 + ((c ^ (qrow & 14)) << 2)] = pk;
      }
    __syncthreads();            // A: QK reads of sK done; V(j) drained; P visible
    if (j < jmax) stageK(j + 1);

    // ---- O^T += V . P^T : A = V frags (d rows), B = P frags (q rows) ----
#pragma unroll
    for (int kc = 0; kc < 2; ++kc) {
      s16x8 vf[8], pf[2];
#pragma unroll
      for (int qt = 0; qt < 2; ++qt) {
        const int qrow = w * 32 + qt * 16 + ln;
        const int c0 = kc * 8 + quad * 2;
        pf[qt] = *(const s16x8*)&sP[qrow * 64 + ((c0 ^ (qrow & 14)) << 2)];
      }
#pragma unroll
      for (int dt = 0; dt < 8; ++dt)
        vf[dt] = *(const s16x8*)&sV[(dt * 16 + ln) * 64 + (((kc * 4 + quad) ^ ln7) << 3)];
#pragma unroll
      for (int dt = 0; dt < 8; ++dt)
#pragma unroll
        for (int qt = 0; qt < 2; ++qt)
          o_acc[dt][qt] = MFMA16(vf[dt], pf[qt], o_acc[dt][qt]);
    }
    __syncthreads();            // B: PV reads of sV done; K(j+1) drained
    if (j < jmax) stageV(j + 1);
  }

  // ---- epilogue: reduce lsum over quads, scale, u16x4 ctx stores ----
  const int b = bh >> 4, h = bh & 15;
  float rinv[2];
#pragma unroll
  for (int qt = 0; qt < 2; ++qt) {
    float s = lsum[qt];
    s += __shfl_xor(s, 16);
    s += __shfl_xor(s, 32);
    rinv[qt] = __builtin_amdgcn_rcpf(s);
  }
#pragma unroll
  for (int dt = 0; dt < 8; ++dt)
#pragma unroll
    for (int qt = 0; qt < 2; ++qt) {
      const int sg = i * 128 + w * 32 + qt * 16 + ln;
      const int d0 = h * 128 + dt * 16 + quad * 4;
      u16x4 ov;
#pragma unroll
      for (int r = 0; r < 4; ++r) ov[r] = f2bf(o_acc[dt][qt][r] * rinv[qt]);
      *(u16x4*)&ctx[((size_t)b << 22) + (size_t)sg * 2048 + d0] = ov;
    }
}

// ---------------- launch ----------------
extern "C" void kernel_launch(void* const* d_in, const int* in_sizes, int n_in,
                              void* d_out, int out_size, void* d_ws, size_t ws_size,
                              hipStream_t stream) {
  const float* x = (const float*)d_in[0];
  const float* Wq = (const float*)d_in[1];
  const float* bq = (const float*)d_in[2];
  const float* Wk = (const float*)d_in[3];
  const float* bk = (const float*)d_in[4];
  const float* Wv = (const float*)d_in[5];
  const float* bv = (const float*)d_in[6];
  const float* Wo = (const float*)d_in[7];
  const float* bo = (const float*)d_in[8];

  u16* ws = (u16*)d_ws;
  u16* xb = ws;
  u16* Wqb = xb + 8388608;
  u16* Wkb = Wqb + 4194304;
  u16* Wvb = Wkb + 4194304;
  u16* Wob = Wvb + 4194304;
  u16* Qb = Wob + 4194304;    // [B,H,S,D] (pre-scaled)
  u16* Kb = Qb + 8388608;     // [B,H,S,D]
  u16* Vtb = Kb + 8388608;    // [B,H,D,S]
  u16* ctxb = Vtb + 8388608;  // [B,S,E]

  cast6<<<dim3(4096, 6), 256, 0, stream>>>(x, Wq, Wk, Wv, Wo, ws);

  gemm_qkv256<<<dim3(8, 16, 3), 512, 0, stream>>>(xb, Wqb, Wkb, Wvb, bq, bk, bv, Qb, Kb, Vtb);

  attn_kernel<<<dim3(16, 32), 256, 0, stream>>>(Qb, Kb, Vtb, ctxb);

  gemm_out<<<dim3(16, 32), 256, 0, stream>>>(ctxb, Wob, bo, (float*)d_out);
}

// Round 3
// 360.414 us; speedup vs baseline: 1.0271x; 1.0271x over previous
//
#include <hip/hip_runtime.h>

typedef unsigned short u16;
typedef __attribute__((ext_vector_type(4))) float f32x4;
typedef __attribute__((ext_vector_type(8))) short s16x8;
typedef __attribute__((ext_vector_type(4))) unsigned short u16x4;

#define MFMA16(a, b, c) __builtin_amdgcn_mfma_f32_16x16x32_bf16((a), (b), (c), 0, 0, 0)

__device__ __forceinline__ u16 f2bf(float f) {
  union { float f; unsigned u; } v; v.f = f;
  unsigned u = v.u;
  u += 0x7fffu + ((u >> 16) & 1u);   // RNE
  return (u16)(u >> 16);
}

__device__ __forceinline__ void gl_lds16(const void* g, void* l) {
  __builtin_amdgcn_global_load_lds(
      (const __attribute__((address_space(1))) void*)g,
      (__attribute__((address_space(3))) void*)l, 16, 0, 0);
}

// ---------------- fused cast fp32 -> bf16 ----------------
__global__ void cast6(const float* __restrict__ x,
                      const float* __restrict__ w0, const float* __restrict__ w1,
                      const float* __restrict__ w2, const float* __restrict__ w3,
                      u16* __restrict__ ws) {
  const int y = blockIdx.y;
  const float* src;
  u16* dst;
  if (y < 2) { src = x + (size_t)y * 4194304; dst = ws + (size_t)y * 4194304; }
  else {
    src = (y == 2) ? w0 : (y == 3) ? w1 : (y == 4) ? w2 : w3;
    dst = ws + 8388608 + (size_t)(y - 2) * 4194304;
  }
  const int i = blockIdx.x * 256 + threadIdx.x;
  f32x4 v = ((const f32x4*)src)[i];
  u16x4 o;
#pragma unroll
  for (int e = 0; e < 4; ++e) o[e] = f2bf(v[e]);
  ((u16x4*)dst)[i] = o;
}

// ---------------- 128x128 GEMM core (proven; used by gemm_out) ----------------
template <int SWAP>
__device__ __forceinline__ void gemm_core(const u16* __restrict__ A,
                                          const u16* __restrict__ Bw,
                                          u16* sA, u16* sB,
                                          f32x4 (&acc)[4][4],
                                          int m0, int n0, int tid) {
  const int lane = tid & 63, w = tid >> 6;
  const int ln = lane & 15, quad = lane >> 4, ln7 = ln & 7;
  const int wm = (w >> 1) * 64, wn = (w & 1) * 64;
  const int srow = lane >> 3;
  const int scol = (((lane & 7) ^ srow)) * 8;

  for (int k0 = 0; k0 < 2048; k0 += 64) {
#pragma unroll
    for (int c = 0; c < 4; ++c) {
      const int chunk = c * 4 + w;
      const int row = chunk * 8 + srow;
      gl_lds16(A + (size_t)(m0 + row) * 2048 + k0 + scol, (char*)sA + chunk * 1024);
      gl_lds16(Bw + (size_t)(n0 + row) * 2048 + k0 + scol, (char*)sB + chunk * 1024);
    }
    __syncthreads();
#pragma unroll
    for (int kk = 0; kk < 64; kk += 32) {
      s16x8 af[4], bf[4];
      const int g = (kk >> 3) + quad;
#pragma unroll
      for (int t = 0; t < 4; ++t) {
        af[t] = *(const s16x8*)&sA[(wm + t * 16 + ln) * 64 + ((g ^ ln7) << 3)];
        bf[t] = *(const s16x8*)&sB[(wn + t * 16 + ln) * 64 + ((g ^ ln7) << 3)];
      }
#pragma unroll
      for (int tm = 0; tm < 4; ++tm)
#pragma unroll
        for (int tn = 0; tn < 4; ++tn)
          acc[tm][tn] = SWAP ? MFMA16(bf[tn], af[tm], acc[tm][tn])
                             : MFMA16(af[tm], bf[tn], acc[tm][tn]);
    }
    __syncthreads();
  }
}

// ---------------- 256x128 8-phase pipelined GEMM core ----------------
// m201-style schedule: per iter = 2 K-tiles (BK=64), 8 phases.
// LDS 96KB = 2 dbuf x (A 256x64 in 2 halves + B 128x64). 8 waves = 4M x 2N,
// per-wave 64x64 out, 4x4 fragments. Stage unit = 16KB = 2 gl_lds16/thread;
// XOR swizzle (row&7) on 16B k-chunks pre-applied to the global source so
// the LDS dest stays linear (gl_lds requirement). Counted vmcnt(4) only at
// phases 3/7 (never 0 in the loop).
template <int SWAP>
__device__ __forceinline__ void gemm8p(const u16* __restrict__ A,
                                       const u16* __restrict__ Bw,
                                       u16* smem, f32x4 (&acc)[4][4],
                                       int m0, int n0, int tid) {
  const int lane = tid & 63, w = tid >> 6;
  const int ln = lane & 15, quad = lane >> 4, ln7 = lane & 7;
  const int sw0 = (quad ^ ln7) << 3, sw1 = ((4 + quad) ^ ln7) << 3;
  const int srow = (w << 3) + (lane >> 3);                 // staged row in unit
  const int scc = ((lane & 7) ^ (lane >> 3)) << 3;         // pre-swizzled src k
  const u16* aRd = smem + (w >> 2) * 8192 + ((w >> 1) & 1) * 4096;
  const u16* bRd = smem + 16384 + (w & 1) * 4096;
  u16* dstW = smem + (w << 9);                             // wave's 1KB chunk

  s16x8 af[4][2], bf[4][2];

  auto STG = [&](const u16* mat, int grow, int t, int dstu) {
    const u16* s0 = mat + (size_t)(grow + srow) * 2048 + ((t & 31) << 6) + scc;
    gl_lds16(s0, dstW + dstu);
    gl_lds16(s0 + 64 * 2048, dstW + dstu + 4096);
  };
  auto RDA = [&](int bo, int tm0) {
#pragma unroll
    for (int u = 0; u < 2; ++u) {
      const int tt = tm0 + u;
      af[tt][0] = *(const s16x8*)&aRd[bo + (tt * 16 + ln) * 64 + sw0];
      af[tt][1] = *(const s16x8*)&aRd[bo + (tt * 16 + ln) * 64 + sw1];
    }
  };
  auto RDB = [&](int bo, int tn0) {
#pragma unroll
    for (int u = 0; u < 2; ++u) {
      const int tt = tn0 + u;
      bf[tt][0] = *(const s16x8*)&bRd[bo + (tt * 16 + ln) * 64 + sw0];
      bf[tt][1] = *(const s16x8*)&bRd[bo + (tt * 16 + ln) * 64 + sw1];
    }
  };
  auto QM = [&](int tm0, int tn0) {
#pragma unroll
    for (int tm = tm0; tm < tm0 + 2; ++tm)
#pragma unroll
      for (int tn = tn0; tn < tn0 + 2; ++tn)
#pragma unroll
        for (int ks = 0; ks < 2; ++ks)
          acc[tm][tn] = SWAP ? MFMA16(bf[tn][ks], af[tm][ks], acc[tm][tn])
                             : MFMA16(af[tm][ks], bf[tn][ks], acc[tm][tn]);
  };

#define PH_MID()                                             \
  __builtin_amdgcn_s_barrier();                              \
  asm volatile("s_waitcnt lgkmcnt(0)" ::: "memory");         \
  __builtin_amdgcn_sched_barrier(0);                         \
  __builtin_amdgcn_s_setprio(1)
#define PH_END()                                             \
  __builtin_amdgcn_s_setprio(0);                             \
  __builtin_amdgcn_s_barrier()
#define PH_ENDV()                                            \
  __builtin_amdgcn_s_setprio(0);                             \
  asm volatile("s_waitcnt vmcnt(4)" ::: "memory");           \
  __builtin_amdgcn_s_barrier()

  // prologue FIFO: A0h0,A0h1,B0 (tile0) | A1h0,A1h1 (tile1 A).
  // vmcnt(4) -> tile0 fully landed; tile1 A still in flight.
  STG(A, m0, 0, 0);
  STG(A, m0 + 128, 0, 8192);
  STG(Bw, n0, 0, 16384);
  STG(A, m0, 1, 24576);
  STG(A, m0 + 128, 1, 24576 + 8192);
  asm volatile("s_waitcnt vmcnt(4)" ::: "memory");
  __builtin_amdgcn_s_barrier();

#pragma unroll 1
  for (int j = 0; j < 16; ++j) {
    const int te = 2 * j + 2, to = 2 * j + 3;  // prefetch tiles (wrap at end)
    // ph0: read e:A01,B01 | stage B1 <- B(2j+1) | mfma Q(0,0)
    RDA(0, 0); RDB(0, 0);
    STG(Bw, n0, 2 * j + 1, 24576 + 16384);
    PH_MID(); QM(0, 0); PH_END();
    // ph1: read e:A23 | mfma Q(2,0)
    RDA(0, 2);
    PH_MID(); QM(2, 0); PH_END();
    // ph2: read e:B23 | stage A0h0 <- A(te) | mfma Q(2,2)
    RDB(0, 2);
    STG(A, m0, te, 0);
    PH_MID(); QM(2, 2); PH_END();
    // ph3: stage A0h1 <- A(te) | mfma Q(0,2) | vmcnt(4): B1+A1 landed
    STG(A, m0 + 128, te, 8192);
    PH_MID(); QM(0, 2); PH_ENDV();
    // ph4: read o:A01,B01 (buf1) | stage B0 <- B(te) | mfma Q(0,0)
    RDA(24576, 0); RDB(24576, 0);
    STG(Bw, n0, te, 16384);
    PH_MID(); QM(0, 0); PH_END();
    // ph5: read o:A23 | mfma Q(2,0)
    RDA(24576, 2);
    PH_MID(); QM(2, 0); PH_END();
    // ph6: read o:B23 | stage A1h0 <- A(to) | mfma Q(2,2)
    RDB(24576, 2);
    STG(A, m0, to, 24576);
    PH_MID(); QM(2, 2); PH_END();
    // ph7: stage A1h1 <- A(to) | mfma Q(0,2) | vmcnt(4): A0+B0 landed
    STG(A, m0 + 128, to, 24576 + 8192);
    PH_MID(); QM(0, 2); PH_ENDV();
  }
  asm volatile("s_waitcnt vmcnt(0)" ::: "memory");  // drain before LDS dealloc
#undef PH_MID
#undef PH_END
#undef PH_ENDV
}

// ---------------- fused Q/K/V projection GEMMs ----------------
// z=0: Q -> [B,H,S,D] bf16 scaled 1/sqrt(D); z=1: K -> [B,H,S,D];
// z=2: V -> Vt [B,H,D,S] bf16 written directly.
__global__ __launch_bounds__(512, 2) void gemm_qkv8(
    const u16* __restrict__ A,
    const u16* __restrict__ W0, const u16* __restrict__ W1, const u16* __restrict__ W2,
    const float* __restrict__ b0, const float* __restrict__ b1, const float* __restrict__ b2,
    u16* __restrict__ Qo, u16* __restrict__ Ko, u16* __restrict__ Vo) {
  __shared__ __align__(16) u16 smem[49152];   // 96 KiB
  const int z = blockIdx.z;
  const u16* Bw = (z == 0) ? W0 : (z == 1) ? W1 : W2;
  const float* bias = (z == 0) ? b0 : (z == 1) ? b1 : b2;

  const int tid = threadIdx.x;
  const int lane = tid & 63, w = tid >> 6;
  const int ln = lane & 15, quad = lane >> 4;
  const int m0 = blockIdx.y * 256, n0 = blockIdx.x * 128;
  const int wm = (w >> 1) * 64, wn = (w & 1) * 64;

  f32x4 acc[4][4] = {};
  if (z < 2) {
    gemm8p<1>(A, Bw, smem, acc, m0, n0, tid);
    u16* out = (z == 0) ? Qo : Ko;
    const float scale = (z == 0) ? 0.08838834764831845f : 1.0f;
#pragma unroll
    for (int tn = 0; tn < 4; ++tn) {
      const int n_base = n0 + wn + tn * 16 + quad * 4;
      const f32x4 bv = *(const f32x4*)&bias[n_base];
      const int h = n_base >> 7, dl = n_base & 127;
#pragma unroll
      for (int tm = 0; tm < 4; ++tm) {
        const int m = m0 + wm + tm * 16 + ln;
        const int b = m >> 11, s = m & 2047;
        u16x4 ov;
#pragma unroll
        for (int r = 0; r < 4; ++r) ov[r] = f2bf((acc[tm][tn][r] + bv[r]) * scale);
        *(u16x4*)&out[(((size_t)(b * 16 + h)) << 18) + ((size_t)s << 7) + dl] = ov;
      }
    }
  } else {
    gemm8p<0>(A, Bw, smem, acc, m0, n0, tid);
    const int b = m0 >> 11;
#pragma unroll
    for (int tn = 0; tn < 4; ++tn) {
      const int n = n0 + wn + tn * 16 + ln;   // global d index
      const float bv = bias[n];
      const int h = n >> 7, dl = n & 127;
#pragma unroll
      for (int tm = 0; tm < 4; ++tm) {
        const int s_base = (m0 & 2047) + wm + tm * 16 + quad * 4;
        u16x4 ov;
#pragma unroll
        for (int r = 0; r < 4; ++r) ov[r] = f2bf(acc[tm][tn][r] + bv);
        *(u16x4*)&Vo[(((size_t)((b * 16 + h) * 128 + dl)) << 11) + s_base] = ov;
      }
    }
  }
}

// ---------------- output projection GEMM (fp32 out, proven 128^2 core) ----------------
__global__ __launch_bounds__(256, 2) void gemm_out(const u16* __restrict__ A,
                                                   const u16* __restrict__ Bw,
                                                   const float* __restrict__ bias,
                                                   float* __restrict__ out) {
  __shared__ __align__(16) u16 smem[16384];
  u16* sA = smem;
  u16* sB = smem + 8192;
  const int tid = threadIdx.x;
  const int lane = tid & 63, w = tid >> 6;
  const int ln = lane & 15, quad = lane >> 4;
  const int m0 = blockIdx.y * 128, n0 = blockIdx.x * 128;
  const int wm = (w >> 1) * 64, wn = (w & 1) * 64;

  f32x4 acc[4][4] = {};
  gemm_core<1>(A, Bw, sA, sB, acc, m0, n0, tid);
#pragma unroll
  for (int tn = 0; tn < 4; ++tn) {
    const int n_base = n0 + wn + tn * 16 + quad * 4;
    const f32x4 bv = *(const f32x4*)&bias[n_base];
#pragma unroll
    for (int tm = 0; tm < 4; ++tm) {
      const int m = m0 + wm + tm * 16 + ln;
      f32x4 ov;
#pragma unroll
      for (int r = 0; r < 4; ++r) ov[r] = acc[tm][tn][r] + bv[r];
      *(f32x4*)&out[(size_t)m * 2048 + n_base] = ov;
    }
  }
}

// ---------------- causal flash attention (S^T orientation) ----------------
// Q,K: [B,H,S,D] bf16 (Q pre-scaled); Vt: [B,H,D,S] bf16. ctx: [B,S,E] bf16.
__global__ __launch_bounds__(256, 2) void attn_kernel(const u16* __restrict__ Q,
                                                      const u16* __restrict__ Kp,
                                                      const u16* __restrict__ Vt,
                                                      u16* __restrict__ ctx) {
  __shared__ __align__(16) u16 smem[24576];  // sP[8192] | sK[8192] | sV[8192]
  u16* sP = smem;
  u16* sK = smem + 8192;
  u16* sV = smem + 16384;

  const int flat = blockIdx.x + (blockIdx.y << 4);
  const int bh = flat >> 4;
  const int i = (flat < 256) ? (15 - (flat & 15)) : (flat & 15);  // pair work-balance
  const size_t base = (size_t)bh << 18;

  const int tid = threadIdx.x, lane = tid & 63, w = tid >> 6;
  const int ln = lane & 15, quad = lane >> 4, ln7 = lane & 7;

  // ---- stage Q tile (32KB) into sK..sV region, swizzled ----
#pragma unroll
  for (int c = 0; c < 8; ++c) {
    const int chunk0 = (c * 4 + w) * 64;
    const int chunk = chunk0 + lane;
    const int row = chunk >> 4, cc = chunk & 15;
    gl_lds16(Q + base + (size_t)((i * 128 + row) * 128 + ((cc ^ (row & 15)) << 3)),
             (char*)sK + chunk0 * 16);
  }
  __syncthreads();
  s16x8 qf[2][4];
#pragma unroll
  for (int qt = 0; qt < 2; ++qt)
#pragma unroll
    for (int kc = 0; kc < 4; ++kc)
      qf[qt][kc] =
          *(const s16x8*)&sK[(w * 32 + qt * 16 + ln) * 128 + (((kc * 4 + quad) ^ ln) << 3)];
  __syncthreads();

  auto stageK = [&](int j) {
#pragma unroll
    for (int c = 0; c < 4; ++c) {
      const int chunk0 = (c * 4 + w) * 64;
      const int chunk = chunk0 + lane;
      const int row = chunk >> 4, cc = chunk & 15;
      gl_lds16(Kp + base + (size_t)((j * 64 + row) * 128 + ((cc ^ (row & 15)) << 3)),
               (char*)sK + chunk0 * 16);
    }
  };
  auto stageV = [&](int j) {
#pragma unroll
    for (int c = 0; c < 4; ++c) {
      const int chunk0 = (c * 4 + w) * 64;
      const int chunk = chunk0 + lane;
      const int row = chunk >> 3, cc = chunk & 7;
      gl_lds16(Vt + base + (size_t)(row * 2048 + j * 64 + ((cc ^ (row & 7)) << 3)),
               (char*)sV + chunk0 * 16);
    }
  };

  stageK(0);
  stageV(0);
  __syncthreads();

  f32x4 o_acc[8][2] = {};
  float lsum[2] = {0.f, 0.f};
  const int jmax = 2 * i + 1;
  const int qg = i * 128 + w * 32 + ln;  // + qt*16 gives lane's global q

  for (int j = 0; j <= jmax; ++j) {
    // ---- S^T = K . Q^T (64k x 128q): A = K frags, B = Q regs ----
    f32x4 sacc[4][2] = {};
#pragma unroll
    for (int kc = 0; kc < 4; ++kc) {
      s16x8 kf[4];
#pragma unroll
      for (int kt = 0; kt < 4; ++kt)
        kf[kt] = *(const s16x8*)&sK[(kt * 16 + ln) * 128 + (((kc * 4 + quad) ^ ln) << 3)];
#pragma unroll
      for (int kt = 0; kt < 4; ++kt)
#pragma unroll
        for (int qt = 0; qt < 2; ++qt)
          sacc[kt][qt] = MFMA16(kf[kt], qf[qt][kc], sacc[kt][qt]);
    }

    // ---- exp + mask + pack P[q][k] via b64 writes (swizzle key q&14) ----
    const bool diag = (j >= 2 * i);
#pragma unroll
    for (int kt = 0; kt < 4; ++kt)
#pragma unroll
      for (int qt = 0; qt < 2; ++qt) {
        u16x4 pk;
#pragma unroll
        for (int r = 0; r < 4; ++r) {
          const int kg = j * 64 + kt * 16 + quad * 4 + r;
          float pv = __expf(sacc[kt][qt][r]);
          if (diag && kg > qg + qt * 16) pv = 0.f;
          lsum[qt] += pv;
          pk[r] = f2bf(pv);
        }
        const int qrow = w * 32 + qt * 16 + ln;
        const int c = kt * 4 + quad;
        *(u16x4*)&sP[qrow * 64 + ((c ^ (qrow & 14)) << 2)] = pk;
      }
    __syncthreads();            // A: QK reads of sK done; V(j) drained; P visible
    if (j < jmax) stageK(j + 1);

    // ---- O^T += V . P^T : A = V frags (d rows), B = P frags (q rows) ----
#pragma unroll
    for (int kc = 0; kc < 2; ++kc) {
      s16x8 vf[8], pf[2];
#pragma unroll
      for (int qt = 0; qt < 2; ++qt) {
        const int qrow = w * 32 + qt * 16 + ln;
        const int c0 = kc * 8 + quad * 2;
        pf[qt] = *(const s16x8*)&sP[qrow * 64 + ((c0 ^ (qrow & 14)) << 2)];
      }
#pragma unroll
      for (int dt = 0; dt < 8; ++dt)
        vf[dt] = *(const s16x8*)&sV[(dt * 16 + ln) * 64 + (((kc * 4 + quad) ^ ln7) << 3)];
#pragma unroll
      for (int dt = 0; dt < 8; ++dt)
#pragma unroll
        for (int qt = 0; qt < 2; ++qt)
          o_acc[dt][qt] = MFMA16(vf[dt], pf[qt], o_acc[dt][qt]);
    }
    __syncthreads();            // B: PV reads of sV done; K(j+1) drained
    if (j < jmax) stageV(j + 1);
  }

  // ---- epilogue: reduce lsum over quads, scale, u16x4 ctx stores ----
  const int b = bh >> 4, h = bh & 15;
  float rinv[2];
#pragma unroll
  for (int qt = 0; qt < 2; ++qt) {
    float s = lsum[qt];
    s += __shfl_xor(s, 16);
    s += __shfl_xor(s, 32);
    rinv[qt] = __builtin_amdgcn_rcpf(s);
  }
#pragma unroll
  for (int dt = 0; dt < 8; ++dt)
#pragma unroll
    for (int qt = 0; qt < 2; ++qt) {
      const int sg = i * 128 + w * 32 + qt * 16 + ln;
      const int d0 = h * 128 + dt * 16 + quad * 4;
      u16x4 ov;
#pragma unroll
      for (int r = 0; r < 4; ++r) ov[r] = f2bf(o_acc[dt][qt][r] * rinv[qt]);
      *(u16x4*)&ctx[((size_t)b << 22) + (size_t)sg * 2048 + d0] = ov;
    }
}

// ---------------- launch ----------------
extern "C" void kernel_launch(void* const* d_in, const int* in_sizes, int n_in,
                              void* d_out, int out_size, void* d_ws, size_t ws_size,
                              hipStream_t stream) {
  const float* x = (const float*)d_in[0];
  const float* Wq = (const float*)d_in[1];
  const float* bq = (const float*)d_in[2];
  const float* Wk = (const float*)d_in[3];
  const float* bk = (const float*)d_in[4];
  const float* Wv = (const float*)d_in[5];
  const float* bv = (const float*)d_in[6];
  const float* Wo = (const float*)d_in[7];
  const float* bo = (const float*)d_in[8];

  u16* ws = (u16*)d_ws;
  u16* xb = ws;
  u16* Wqb = xb + 8388608;
  u16* Wkb = Wqb + 4194304;
  u16* Wvb = Wkb + 4194304;
  u16* Wob = Wvb + 4194304;
  u16* Qb = Wob + 4194304;    // [B,H,S,D] (pre-scaled)
  u16* Kb = Qb + 8388608;     // [B,H,S,D]
  u16* Vtb = Kb + 8388608;    // [B,H,D,S]
  u16* ctxb = Vtb + 8388608;  // [B,S,E]

  cast6<<<dim3(4096, 6), 256, 0, stream>>>(x, Wq, Wk, Wv, Wo, ws);

  gemm_qkv8<<<dim3(16, 16, 3), 512, 0, stream>>>(xb, Wqb, Wkb, Wvb, bq, bk, bv, Qb, Kb, Vtb);

  attn_kernel<<<dim3(16, 32), 256, 0, stream>>>(Qb, Kb, Vtb, ctxb);

  gemm_out<<<dim3(16, 32), 256, 0, stream>>>(ctxb, Wob, bo, (float*)d_out);
}

// Round 4
// 359.486 us; speedup vs baseline: 1.0298x; 1.0026x over previous
//
#include <hip/hip_runtime.h>

typedef unsigned short u16;
typedef __attribute__((ext_vector_type(4))) float f32x4;
typedef __attribute__((ext_vector_type(8))) short s16x8;
typedef __attribute__((ext_vector_type(4))) unsigned short u16x4;

#define MFMA16(a, b, c) __builtin_amdgcn_mfma_f32_16x16x32_bf16((a), (b), (c), 0, 0, 0)

__device__ __forceinline__ u16 f2bf(float f) {
  union { float f; unsigned u; } v; v.f = f;
  unsigned u = v.u;
  u += 0x7fffu + ((u >> 16) & 1u);   // RNE
  return (u16)(u >> 16);
}

__device__ __forceinline__ void gl_lds16(const void* g, void* l) {
  __builtin_amdgcn_global_load_lds(
      (const __attribute__((address_space(1))) void*)g,
      (__attribute__((address_space(3))) void*)l, 16, 0, 0);
}

// ---------------- fused cast fp32 -> bf16 ----------------
__global__ void cast6(const float* __restrict__ x,
                      const float* __restrict__ w0, const float* __restrict__ w1,
                      const float* __restrict__ w2, const float* __restrict__ w3,
                      u16* __restrict__ ws) {
  const int y = blockIdx.y;
  const float* src;
  u16* dst;
  if (y < 2) { src = x + (size_t)y * 4194304; dst = ws + (size_t)y * 4194304; }
  else {
    src = (y == 2) ? w0 : (y == 3) ? w1 : (y == 4) ? w2 : w3;
    dst = ws + 8388608 + (size_t)(y - 2) * 4194304;
  }
  const int i = blockIdx.x * 256 + threadIdx.x;
  f32x4 v = ((const f32x4*)src)[i];
  u16x4 o;
#pragma unroll
  for (int e = 0; e < 4; ++e) o[e] = f2bf(v[e]);
  ((u16x4*)dst)[i] = o;
}

// ---------------- 128x128 GEMM core (proven; gemm_v + gemm_out) ----------------
template <int SWAP>
__device__ __forceinline__ void gemm_core(const u16* __restrict__ A,
                                          const u16* __restrict__ Bw,
                                          u16* sA, u16* sB,
                                          f32x4 (&acc)[4][4],
                                          int m0, int n0, int tid) {
  const int lane = tid & 63, w = tid >> 6;
  const int ln = lane & 15, quad = lane >> 4, ln7 = ln & 7;
  const int wm = (w >> 1) * 64, wn = (w & 1) * 64;
  const int srow = lane >> 3;
  const int scol = (((lane & 7) ^ srow)) * 8;

  for (int k0 = 0; k0 < 2048; k0 += 64) {
#pragma unroll
    for (int c = 0; c < 4; ++c) {
      const int chunk = c * 4 + w;
      const int row = chunk * 8 + srow;
      gl_lds16(A + (size_t)(m0 + row) * 2048 + k0 + scol, (char*)sA + chunk * 1024);
      gl_lds16(Bw + (size_t)(n0 + row) * 2048 + k0 + scol, (char*)sB + chunk * 1024);
    }
    __syncthreads();
#pragma unroll
    for (int kk = 0; kk < 64; kk += 32) {
      s16x8 af[4], bf[4];
      const int g = (kk >> 3) + quad;
#pragma unroll
      for (int t = 0; t < 4; ++t) {
        af[t] = *(const s16x8*)&sA[(wm + t * 16 + ln) * 64 + ((g ^ ln7) << 3)];
        bf[t] = *(const s16x8*)&sB[(wn + t * 16 + ln) * 64 + ((g ^ ln7) << 3)];
      }
#pragma unroll
      for (int tm = 0; tm < 4; ++tm)
#pragma unroll
        for (int tn = 0; tn < 4; ++tn)
          acc[tm][tn] = SWAP ? MFMA16(bf[tn], af[tm], acc[tm][tn])
                             : MFMA16(af[tm], bf[tn], acc[tm][tn]);
    }
    __syncthreads();
  }
}

// ---------------- 256x256 8-phase Q/K GEMM (m201 geometry) ----------------
// 8 waves (2M x 4N), per-wave 128x64 -> 24 ds_read_b128 per 64 MFMA per
// K-tile (MFMA-bound pipe ratio). LDS 128 KiB = 2 buf x {A0,A1,B0,B1} 16KB
// units. Per iter = 2 K-tiles = 8 phases of 16 MFMA (one C-quadrant).
// Stage 2 units per stage-point; counted vmcnt(4) at ph3/ph7 only (leash
// 3-4 phases). Source columns pre-swizzled (chunk ^ (row&7)) so LDS dest
// stays linear and frag reads use the measured-0-conflict pattern.
__global__ __launch_bounds__(512, 2) void gemm_qk256(
    const u16* __restrict__ A,
    const u16* __restrict__ W0, const u16* __restrict__ W1,
    const float* __restrict__ b0, const float* __restrict__ b1,
    u16* __restrict__ Qo, u16* __restrict__ Ko) {
  __shared__ __align__(16) u16 smem[65536];   // 128 KiB
  const int z = blockIdx.z;
  const u16* Bw = z ? W1 : W0;
  const float* bias = z ? b1 : b0;
  u16* out = z ? Ko : Qo;
  const float scale = z ? 1.0f : 0.08838834764831845f;

  const int tid = threadIdx.x;
  const int lane = tid & 63, w = tid >> 6;
  const int ln = lane & 15, quad = lane >> 4, ln7 = lane & 7;
  const int m0 = blockIdx.y * 256, n0 = blockIdx.x * 256;
  const int wm = (w >> 2) << 7, wn = (w & 3) << 6;

  // staging: 2 chunk-loads per thread per 16KB unit (128 rows x 8 chunks)
  const int ci0 = tid, ci1 = 512 + tid;
  const int r0 = ci0 >> 3, c0k = ((ci0 & 7) ^ (r0 & 7)) << 3;
  const int r1 = ci1 >> 3, c1k = ((ci1 & 7) ^ (r1 & 7)) << 3;
  // frag read bases (u16), buf offset excluded
  const int abase = (w >> 2) << 13;                                   // A half
  const int bbase = 16384 + (((w >> 1) & 1) << 13) + ((w & 1) << 12); // B half+qtr
  const int sw0 = (quad ^ ln7) << 3, sw1 = ((4 + quad) ^ ln7) << 3;

  f32x4 acc[8][4] = {};
  s16x8 af[8][2], bf[4][2];

  auto STGA = [&](int t) {  // A both halves -> buf(t&1) : 4 loads
    u16* dst = smem + ((t & 1) << 15);
    const int kc = (t & 31) << 6;
    const u16* s0 = A + (size_t)(m0 + r0) * 2048 + kc + c0k;
    const u16* s1 = A + (size_t)(m0 + r1) * 2048 + kc + c1k;
    gl_lds16(s0, dst + ci0 * 8);
    gl_lds16(s1, dst + ci1 * 8);
    gl_lds16(s0 + (size_t)128 * 2048, dst + 8192 + ci0 * 8);
    gl_lds16(s1 + (size_t)128 * 2048, dst + 8192 + ci1 * 8);
  };
  auto STGB = [&](int t) {  // B both halves -> buf(t&1)+16384 : 4 loads
    u16* dst = smem + ((t & 1) << 15) + 16384;
    const int kc = (t & 31) << 6;
    const u16* s0 = Bw + (size_t)(n0 + r0) * 2048 + kc + c0k;
    const u16* s1 = Bw + (size_t)(n0 + r1) * 2048 + kc + c1k;
    gl_lds16(s0, dst + ci0 * 8);
    gl_lds16(s1, dst + ci1 * 8);
    gl_lds16(s0 + (size_t)128 * 2048, dst + 8192 + ci0 * 8);
    gl_lds16(s1 + (size_t)128 * 2048, dst + 8192 + ci1 * 8);
  };
  auto RDA = [&](int buf, int tm0) {  // 4 frags x 2 ks = 8 reads
    const u16* p = smem + (buf << 15) + abase;
#pragma unroll
    for (int u = 0; u < 4; ++u) {
      const int tt = tm0 + u;
      af[tt][0] = *(const s16x8*)&p[(tt * 16 + ln) * 64 + sw0];
      af[tt][1] = *(const s16x8*)&p[(tt * 16 + ln) * 64 + sw1];
    }
  };
  auto RDB = [&](int buf, int tn0) {  // 2 frags x 2 ks = 4 reads
    const u16* p = smem + (buf << 15) + bbase;
#pragma unroll
    for (int u = 0; u < 2; ++u) {
      const int tt = tn0 + u;
      bf[tt][0] = *(const s16x8*)&p[(tt * 16 + ln) * 64 + sw0];
      bf[tt][1] = *(const s16x8*)&p[(tt * 16 + ln) * 64 + sw1];
    }
  };
  auto QM = [&](int tm0, int tn0) {  // 4x2x2 = 16 MFMA
#pragma unroll
    for (int tm = tm0; tm < tm0 + 4; ++tm)
#pragma unroll
      for (int tn = tn0; tn < tn0 + 2; ++tn)
#pragma unroll
        for (int ks = 0; ks < 2; ++ks)
          acc[tm][tn] = MFMA16(bf[tn][ks], af[tm][ks], acc[tm][tn]);
  };

#define PH_MID()                                             \
  __builtin_amdgcn_s_barrier();                              \
  asm volatile("s_waitcnt lgkmcnt(0)" ::: "memory");         \
  __builtin_amdgcn_sched_barrier(0);                         \
  __builtin_amdgcn_s_setprio(1)
#define PH_END()                                             \
  __builtin_amdgcn_s_setprio(0);                             \
  __builtin_amdgcn_s_barrier()
#define PH_ENDV()                                            \
  __builtin_amdgcn_s_setprio(0);                             \
  asm volatile("s_waitcnt vmcnt(4)" ::: "memory");           \
  __builtin_amdgcn_s_barrier()

  // prologue: tile0 (8 loads) + tile1 A (4). vmcnt(4) -> tile0 landed.
  STGA(0); STGB(0); STGA(1);
  asm volatile("s_waitcnt vmcnt(4)" ::: "memory");
  __builtin_amdgcn_s_barrier();

  // FIFO (loads/thread): after prologue in-flight = A(1):4.
  // iter j: ph0 +B(2j+1) -> 8; ph3 +A(2j+2) -> 12, vmcnt(4) retires
  // A(2j+1),B(2j+1) [tile 2j+1 ready for ph4]; ph4 +B(2j+2) -> 8;
  // ph7 +A(2j+3) -> 12, vmcnt(4) retires tile 2j+2 [ready for next ph0].
  // Write-after-read: buf0 reads sealed by ph2-end (all lgkmcnt'd), buf1
  // by ph6-end; stages into buf0 at ph3/ph4, buf1 at ph7/ph0'. Tail wraps
  // t&31 (junk prefetch of tile 0/1 data into dead buffers; drained below).
#pragma unroll 1
  for (int j = 0; j < 16; ++j) {
    const int t = 2 * j;
    // ph0: quadrant (tm0-3, tn0-1) of tile t (buf0)
    RDA(0, 0); RDB(0, 0);
    STGB(t + 1);
    PH_MID(); QM(0, 0); PH_END();
    // ph1: (tm4-7, tn0-1)
    RDA(0, 4);
    PH_MID(); QM(4, 0); PH_END();
    // ph2: (tm4-7, tn2-3)
    RDB(0, 2);
    PH_MID(); QM(4, 2); PH_END();
    // ph3: (tm0-3, tn2-3) | stage A(t+2) | vmcnt(4)
    STGA(t + 2);
    PH_MID(); QM(0, 2); PH_ENDV();
    // ph4: tile t+1 (buf1)
    RDA(1, 0); RDB(1, 0);
    STGB(t + 2);
    PH_MID(); QM(0, 0); PH_END();
    // ph5
    RDA(1, 4);
    PH_MID(); QM(4, 0); PH_END();
    // ph6
    RDB(1, 2);
    PH_MID(); QM(4, 2); PH_END();
    // ph7: stage A(t+3) | vmcnt(4)
    STGA(t + 3);
    PH_MID(); QM(0, 2); PH_ENDV();
  }
  asm volatile("s_waitcnt vmcnt(0)" ::: "memory");  // drain junk before dealloc
#undef PH_MID
#undef PH_END
#undef PH_ENDV

  // epilogue: D rows = n (quad*4+r), cols = m (ln); [B,H,S,D] store
#pragma unroll
  for (int tn = 0; tn < 4; ++tn) {
    const int n_base = n0 + wn + tn * 16 + quad * 4;
    const f32x4 bv = *(const f32x4*)&bias[n_base];
    const int h = n_base >> 7, dl = n_base & 127;
#pragma unroll
    for (int tm = 0; tm < 8; ++tm) {
      const int m = m0 + wm + tm * 16 + ln;
      const int b = m >> 11, s = m & 2047;
      u16x4 ov;
#pragma unroll
      for (int r = 0; r < 4; ++r) ov[r] = f2bf((acc[tm][tn][r] + bv[r]) * scale);
      *(u16x4*)&out[(((size_t)(b * 16 + h)) << 18) + ((size_t)s << 7) + dl] = ov;
    }
  }
}

// ---------------- V projection GEMM (proven 128^2 core, transposed out) ----------------
__global__ __launch_bounds__(256, 2) void gemm_v(const u16* __restrict__ A,
                                                 const u16* __restrict__ Bw,
                                                 const float* __restrict__ bias,
                                                 u16* __restrict__ Vo) {
  __shared__ __align__(16) u16 smem[16384];
  u16* sA = smem;
  u16* sB = smem + 8192;
  const int tid = threadIdx.x;
  const int lane = tid & 63, w = tid >> 6;
  const int ln = lane & 15, quad = lane >> 4;
  const int m0 = blockIdx.y * 128, n0 = blockIdx.x * 128;
  const int wm = (w >> 1) * 64, wn = (w & 1) * 64;

  f32x4 acc[4][4] = {};
  gemm_core<0>(A, Bw, sA, sB, acc, m0, n0, tid);
  const int b = m0 >> 11;
#pragma unroll
  for (int tn = 0; tn < 4; ++tn) {
    const int n = n0 + wn + tn * 16 + ln;   // global d index
    const float bv = bias[n];
    const int h = n >> 7, dl = n & 127;
#pragma unroll
    for (int tm = 0; tm < 4; ++tm) {
      const int s_base = (m0 & 2047) + wm + tm * 16 + quad * 4;
      u16x4 ov;
#pragma unroll
      for (int r = 0; r < 4; ++r) ov[r] = f2bf(acc[tm][tn][r] + bv);
      *(u16x4*)&Vo[(((size_t)((b * 16 + h) * 128 + dl)) << 11) + s_base] = ov;
    }
  }
}

// ---------------- output projection GEMM (fp32 out, proven 128^2 core) ----------------
__global__ __launch_bounds__(256, 2) void gemm_out(const u16* __restrict__ A,
                                                   const u16* __restrict__ Bw,
                                                   const float* __restrict__ bias,
                                                   float* __restrict__ out) {
  __shared__ __align__(16) u16 smem[16384];
  u16* sA = smem;
  u16* sB = smem + 8192;
  const int tid = threadIdx.x;
  const int lane = tid & 63, w = tid >> 6;
  const int ln = lane & 15, quad = lane >> 4;
  const int m0 = blockIdx.y * 128, n0 = blockIdx.x * 128;
  const int wm = (w >> 1) * 64, wn = (w & 1) * 64;

  f32x4 acc[4][4] = {};
  gemm_core<1>(A, Bw, sA, sB, acc, m0, n0, tid);
#pragma unroll
  for (int tn = 0; tn < 4; ++tn) {
    const int n_base = n0 + wn + tn * 16 + quad * 4;
    const f32x4 bv = *(const f32x4*)&bias[n_base];
#pragma unroll
    for (int tm = 0; tm < 4; ++tm) {
      const int m = m0 + wm + tm * 16 + ln;
      f32x4 ov;
#pragma unroll
      for (int r = 0; r < 4; ++r) ov[r] = acc[tm][tn][r] + bv[r];
      *(f32x4*)&out[(size_t)m * 2048 + n_base] = ov;
    }
  }
}

// ---------------- causal flash attention (S^T orientation) ----------------
// Q,K: [B,H,S,D] bf16 (Q pre-scaled); Vt: [B,H,D,S] bf16. ctx: [B,S,E] bf16.
__global__ __launch_bounds__(256, 2) void attn_kernel(const u16* __restrict__ Q,
                                                      const u16* __restrict__ Kp,
                                                      const u16* __restrict__ Vt,
                                                      u16* __restrict__ ctx) {
  __shared__ __align__(16) u16 smem[24576];  // sP[8192] | sK[8192] | sV[8192]
  u16* sP = smem;
  u16* sK = smem + 8192;
  u16* sV = smem + 16384;

  const int flat = blockIdx.x + (blockIdx.y << 4);
  const int bh = flat >> 4;
  const int i = (flat < 256) ? (15 - (flat & 15)) : (flat & 15);  // pair work-balance
  const size_t base = (size_t)bh << 18;

  const int tid = threadIdx.x, lane = tid & 63, w = tid >> 6;
  const int ln = lane & 15, quad = lane >> 4, ln7 = lane & 7;

  // ---- stage Q tile (32KB) into sK..sV region, swizzled ----
#pragma unroll
  for (int c = 0; c < 8; ++c) {
    const int chunk0 = (c * 4 + w) * 64;
    const int chunk = chunk0 + lane;
    const int row = chunk >> 4, cc = chunk & 15;
    gl_lds16(Q + base + (size_t)((i * 128 + row) * 128 + ((cc ^ (row & 15)) << 3)),
             (char*)sK + chunk0 * 16);
  }
  __syncthreads();
  s16x8 qf[2][4];
#pragma unroll
  for (int qt = 0; qt < 2; ++qt)
#pragma unroll
    for (int kc = 0; kc < 4; ++kc)
      qf[qt][kc] =
          *(const s16x8*)&sK[(w * 32 + qt * 16 + ln) * 128 + (((kc * 4 + quad) ^ ln) << 3)];
  __syncthreads();

  auto stageK = [&](int j) {
#pragma unroll
    for (int c = 0; c < 4; ++c) {
      const int chunk0 = (c * 4 + w) * 64;
      const int chunk = chunk0 + lane;
      const int row = chunk >> 4, cc = chunk & 15;
      gl_lds16(Kp + base + (size_t)((j * 64 + row) * 128 + ((cc ^ (row & 15)) << 3)),
               (char*)sK + chunk0 * 16);
    }
  };
  auto stageV = [&](int j) {
#pragma unroll
    for (int c = 0; c < 4; ++c) {
      const int chunk0 = (c * 4 + w) * 64;
      const int chunk = chunk0 + lane;
      const int row = chunk >> 3, cc = chunk & 7;
      gl_lds16(Vt + base + (size_t)(row * 2048 + j * 64 + ((cc ^ (row & 7)) << 3)),
               (char*)sV + chunk0 * 16);
    }
  };

  stageK(0);
  stageV(0);
  __syncthreads();

  f32x4 o_acc[8][2] = {};
  float lsum[2] = {0.f, 0.f};
  const int jmax = 2 * i + 1;
  const int qg = i * 128 + w * 32 + ln;  // + qt*16 gives lane's global q

  for (int j = 0; j <= jmax; ++j) {
    // ---- S^T = K . Q^T (64k x 128q): A = K frags, B = Q regs ----
    f32x4 sacc[4][2] = {};
#pragma unroll
    for (int kc = 0; kc < 4; ++kc) {
      s16x8 kf[4];
#pragma unroll
      for (int kt = 0; kt < 4; ++kt)
        kf[kt] = *(const s16x8*)&sK[(kt * 16 + ln) * 128 + (((kc * 4 + quad) ^ ln) << 3)];
#pragma unroll
      for (int kt = 0; kt < 4; ++kt)
#pragma unroll
        for (int qt = 0; qt < 2; ++qt)
          sacc[kt][qt] = MFMA16(kf[kt], qf[qt][kc], sacc[kt][qt]);
    }

    // ---- exp + mask + pack P[q][k] via b64 writes (swizzle key q&14) ----
    const bool diag = (j >= 2 * i);
#pragma unroll
    for (int kt = 0; kt < 4; ++kt)
#pragma unroll
      for (int qt = 0; qt < 2; ++qt) {
        u16x4 pk;
#pragma unroll
        for (int r = 0; r < 4; ++r) {
          const int kg = j * 64 + kt * 16 + quad * 4 + r;
          float pv = __expf(sacc[kt][qt][r]);
          if (diag && kg > qg + qt * 16) pv = 0.f;
          lsum[qt] += pv;
          pk[r] = f2bf(pv);
        }
        const int qrow = w * 32 + qt * 16 + ln;
        const int c = kt * 4 + quad;
        *(u16x4*)&sP[qrow * 64 + ((c ^ (qrow & 14)) << 2)] = pk;
      }
    __syncthreads();            // A: QK reads of sK done; V(j) drained; P visible
    if (j < jmax) stageK(j + 1);

    // ---- O^T += V . P^T : A = V frags (d rows), B = P frags (q rows) ----
#pragma unroll
    for (int kc = 0; kc < 2; ++kc) {
      s16x8 vf[8], pf[2];
#pragma unroll
      for (int qt = 0; qt < 2; ++qt) {
        const int qrow = w * 32 + qt * 16 + ln;
        const int c0 = kc * 8 + quad * 2;
        pf[qt] = *(const s16x8*)&sP[qrow * 64 + ((c0 ^ (qrow & 14)) << 2)];
      }
#pragma unroll
      for (int dt = 0; dt < 8; ++dt)
        vf[dt] = *(const s16x8*)&sV[(dt * 16 + ln) * 64 + (((kc * 4 + quad) ^ ln7) << 3)];
#pragma unroll
      for (int dt = 0; dt < 8; ++dt)
#pragma unroll
        for (int qt = 0; qt < 2; ++qt)
          o_acc[dt][qt] = MFMA16(vf[dt], pf[qt], o_acc[dt][qt]);
    }
    __syncthreads();            // B: PV reads of sV done; K(j+1) drained
    if (j < jmax) stageV(j + 1);
  }

  // ---- epilogue: reduce lsum over quads, scale, u16x4 ctx stores ----
  const int b = bh >> 4, h = bh & 15;
  float rinv[2];
#pragma unroll
  for (int qt = 0; qt < 2; ++qt) {
    float s = lsum[qt];
    s += __shfl_xor(s, 16);
    s += __shfl_xor(s, 32);
    rinv[qt] = __builtin_amdgcn_rcpf(s);
  }
#pragma unroll
  for (int dt = 0; dt < 8; ++dt)
#pragma unroll
    for (int qt = 0; qt < 2; ++qt) {
      const int sg = i * 128 + w * 32 + qt * 16 + ln;
      const int d0 = h * 128 + dt * 16 + quad * 4;
      u16x4 ov;
#pragma unroll
      for (int r = 0; r < 4; ++r) ov[r] = f2bf(o_acc[dt][qt][r] * rinv[qt]);
      *(u16x4*)&ctx[((size_t)b << 22) + (size_t)sg * 2048 + d0] = ov;
    }
}

// ---------------- launch ----------------
extern "C" void kernel_launch(void* const* d_in, const int* in_sizes, int n_in,
                              void* d_out, int out_size, void* d_ws, size_t ws_size,
                              hipStream_t stream) {
  const float* x = (const float*)d_in[0];
  const float* Wq = (const float*)d_in[1];
  const float* bq = (const float*)d_in[2];
  const float* Wk = (const float*)d_in[3];
  const float* bk = (const float*)d_in[4];
  const float* Wv = (const float*)d_in[5];
  const float* bv = (const float*)d_in[6];
  const float* Wo = (const float*)d_in[7];
  const float* bo = (const float*)d_in[8];

  u16* ws = (u16*)d_ws;
  u16* xb = ws;
  u16* Wqb = xb + 8388608;
  u16* Wkb = Wqb + 4194304;
  u16* Wvb = Wkb + 4194304;
  u16* Wob = Wvb + 4194304;
  u16* Qb = Wob + 4194304;    // [B,H,S,D] (pre-scaled)
  u16* Kb = Qb + 8388608;     // [B,H,S,D]
  u16* Vtb = Kb + 8388608;    // [B,H,D,S]
  u16* ctxb = Vtb + 8388608;  // [B,S,E]

  cast6<<<dim3(4096, 6), 256, 0, stream>>>(x, Wq, Wk, Wv, Wo, ws);

  gemm_qk256<<<dim3(8, 16, 2), 512, 0, stream>>>(xb, Wqb, Wkb, bq, bk, Qb, Kb);
  gemm_v<<<dim3(16, 32), 256, 0, stream>>>(xb, Wvb, bv, Vtb);

  attn_kernel<<<dim3(16, 32), 256, 0, stream>>>(Qb, Kb, Vtb, ctxb);

  gemm_out<<<dim3(16, 32), 256, 0, stream>>>(ctxb, Wob, bo, (float*)d_out);
}

// Round 5
// 356.207 us; speedup vs baseline: 1.0393x; 1.0092x over previous
//
#include <hip/hip_runtime.h>

typedef unsigned short u16;
typedef __attribute__((ext_vector_type(4))) float f32x4;
typedef __attribute__((ext_vector_type(8))) short s16x8;
typedef __attribute__((ext_vector_type(4))) unsigned short u16x4;

#define MFMA16(a, b, c) __builtin_amdgcn_mfma_f32_16x16x32_bf16((a), (b), (c), 0, 0, 0)

__device__ __forceinline__ u16 f2bf(float f) {
  union { float f; unsigned u; } v; v.f = f;
  unsigned u = v.u;
  u += 0x7fffu + ((u >> 16) & 1u);   // RNE
  return (u16)(u >> 16);
}

__device__ __forceinline__ void gl_lds16(const void* g, void* l) {
  __builtin_amdgcn_global_load_lds(
      (const __attribute__((address_space(1))) void*)g,
      (__attribute__((address_space(3))) void*)l, 16, 0, 0);
}

// ---------------- fused cast fp32 -> bf16 ----------------
__global__ void cast6(const float* __restrict__ x,
                      const float* __restrict__ w0, const float* __restrict__ w1,
                      const float* __restrict__ w2, const float* __restrict__ w3,
                      u16* __restrict__ ws) {
  const int y = blockIdx.y;
  const float* src;
  u16* dst;
  if (y < 2) { src = x + (size_t)y * 4194304; dst = ws + (size_t)y * 4194304; }
  else {
    src = (y == 2) ? w0 : (y == 3) ? w1 : (y == 4) ? w2 : w3;
    dst = ws + 8388608 + (size_t)(y - 2) * 4194304;
  }
  const int i = blockIdx.x * 256 + threadIdx.x;
  f32x4 v = ((const f32x4*)src)[i];
  u16x4 o;
#pragma unroll
  for (int e = 0; e < 4; ++e) o[e] = f2bf(v[e]);
  ((u16x4*)dst)[i] = o;
}

// ---------------- 128x128 GEMM core (proven; gemm_v + gemm_out) ----------------
template <int SWAP>
__device__ __forceinline__ void gemm_core(const u16* __restrict__ A,
                                          const u16* __restrict__ Bw,
                                          u16* sA, u16* sB,
                                          f32x4 (&acc)[4][4],
                                          int m0, int n0, int tid) {
  const int lane = tid & 63, w = tid >> 6;
  const int ln = lane & 15, quad = lane >> 4, ln7 = ln & 7;
  const int wm = (w >> 1) * 64, wn = (w & 1) * 64;
  const int srow = lane >> 3;
  const int scol = (((lane & 7) ^ srow)) * 8;

  for (int k0 = 0; k0 < 2048; k0 += 64) {
#pragma unroll
    for (int c = 0; c < 4; ++c) {
      const int chunk = c * 4 + w;
      const int row = chunk * 8 + srow;
      gl_lds16(A + (size_t)(m0 + row) * 2048 + k0 + scol, (char*)sA + chunk * 1024);
      gl_lds16(Bw + (size_t)(n0 + row) * 2048 + k0 + scol, (char*)sB + chunk * 1024);
    }
    __syncthreads();
#pragma unroll
    for (int kk = 0; kk < 64; kk += 32) {
      s16x8 af[4], bf[4];
      const int g = (kk >> 3) + quad;
#pragma unroll
      for (int t = 0; t < 4; ++t) {
        af[t] = *(const s16x8*)&sA[(wm + t * 16 + ln) * 64 + ((g ^ ln7) << 3)];
        bf[t] = *(const s16x8*)&sB[(wn + t * 16 + ln) * 64 + ((g ^ ln7) << 3)];
      }
#pragma unroll
      for (int tm = 0; tm < 4; ++tm)
#pragma unroll
        for (int tn = 0; tn < 4; ++tn)
          acc[tm][tn] = SWAP ? MFMA16(bf[tn], af[tm], acc[tm][tn])
                             : MFMA16(af[tm], bf[tn], acc[tm][tn]);
    }
    __syncthreads();
  }
}

// ---------------- 256x256 single-barrier-phase Q/K GEMM ----------------
// 8 waves (2M x 4N), per-wave 128x64; 24 ds_read_b128 / 64 MFMA per K-tile.
// LDS 128 KiB = 2 buf x {A 32K | B 32K}. One barrier per phase; each phase:
// {MFMA quadrant (compiler lgkm-gated on reads issued LAST phase) ; issue
// next phase's frag reads ; optional stage/seal ; s_barrier}. Reads overlap
// the previous phase's MFMA drain. vmcnt(0) seal once per tile at ph2,
// retiring only loads issued 2-3 phases earlier (stale -> cheap).
__global__ __launch_bounds__(512, 2) void gemm_qk256(
    const u16* __restrict__ A,
    const u16* __restrict__ W0, const u16* __restrict__ W1,
    const float* __restrict__ b0, const float* __restrict__ b1,
    u16* __restrict__ Qo, u16* __restrict__ Ko) {
  __shared__ __align__(16) u16 smem[65536];   // 128 KiB
  const int z = blockIdx.z;
  const u16* Bw = z ? W1 : W0;
  const float* bias = z ? b1 : b0;
  u16* out = z ? Ko : Qo;
  const float scale = z ? 1.0f : 0.08838834764831845f;

  const int tid = threadIdx.x;
  const int lane = tid & 63, w = tid >> 6;
  const int ln = lane & 15, quad = lane >> 4, ln7 = lane & 7;
  const int m0 = blockIdx.y * 256, n0 = blockIdx.x * 256;
  const int wm = (w >> 2) << 7, wn = (w & 3) << 6;

  // staging: 2 chunk-loads per thread per 16KB unit (128 rows x 8 chunks)
  const int ci0 = tid, ci1 = 512 + tid;
  const int r0 = ci0 >> 3, c0k = ((ci0 & 7) ^ (r0 & 7)) << 3;
  const int r1 = ci1 >> 3, c1k = ((ci1 & 7) ^ (r1 & 7)) << 3;
  // frag read bases (u16), buf offset excluded
  const int abase = (w >> 2) << 13;                                   // A half
  const int bbase = 16384 + (((w >> 1) & 1) << 13) + ((w & 1) << 12); // B half+qtr
  const int sw0 = (quad ^ ln7) << 3, sw1 = ((4 + quad) ^ ln7) << 3;

  f32x4 acc[8][4] = {};
  s16x8 af[8][2], bf[4][2];

  auto STGA = [&](int t) {  // A both halves -> buf(t&1) : 4 loads
    u16* dst = smem + ((t & 1) << 15);
    const int kc = (t & 31) << 6;
    const u16* s0 = A + (size_t)(m0 + r0) * 2048 + kc + c0k;
    const u16* s1 = A + (size_t)(m0 + r1) * 2048 + kc + c1k;
    gl_lds16(s0, dst + ci0 * 8);
    gl_lds16(s1, dst + ci1 * 8);
    gl_lds16(s0 + (size_t)128 * 2048, dst + 8192 + ci0 * 8);
    gl_lds16(s1 + (size_t)128 * 2048, dst + 8192 + ci1 * 8);
  };
  auto STGB = [&](int t) {  // B both halves -> buf(t&1)+16384 : 4 loads
    u16* dst = smem + ((t & 1) << 15) + 16384;
    const int kc = (t & 31) << 6;
    const u16* s0 = Bw + (size_t)(n0 + r0) * 2048 + kc + c0k;
    const u16* s1 = Bw + (size_t)(n0 + r1) * 2048 + kc + c1k;
    gl_lds16(s0, dst + ci0 * 8);
    gl_lds16(s1, dst + ci1 * 8);
    gl_lds16(s0 + (size_t)128 * 2048, dst + 8192 + ci0 * 8);
    gl_lds16(s1 + (size_t)128 * 2048, dst + 8192 + ci1 * 8);
  };
  auto RDA = [&](int buf, int tm0) {  // 4 frags x 2 ks = 8 reads
    const u16* p = smem + (buf << 15) + abase;
#pragma unroll
    for (int u = 0; u < 4; ++u) {
      const int tt = tm0 + u;
      af[tt][0] = *(const s16x8*)&p[(tt * 16 + ln) * 64 + sw0];
      af[tt][1] = *(const s16x8*)&p[(tt * 16 + ln) * 64 + sw1];
    }
  };
  auto RDB = [&](int buf, int tn0) {  // 2 frags x 2 ks = 4 reads
    const u16* p = smem + (buf << 15) + bbase;
#pragma unroll
    for (int u = 0; u < 2; ++u) {
      const int tt = tn0 + u;
      bf[tt][0] = *(const s16x8*)&p[(tt * 16 + ln) * 64 + sw0];
      bf[tt][1] = *(const s16x8*)&p[(tt * 16 + ln) * 64 + sw1];
    }
  };
  auto QM = [&](int tm0, int tn0) {  // 4x2x2 = 16 MFMA (one C-quadrant)
    __builtin_amdgcn_s_setprio(1);
#pragma unroll
    for (int tm = tm0; tm < tm0 + 4; ++tm)
#pragma unroll
      for (int tn = tn0; tn < tn0 + 2; ++tn)
#pragma unroll
        for (int ks = 0; ks < 2; ++ks)
          acc[tm][tn] = MFMA16(bf[tn][ks], af[tm][ks], acc[tm][tn]);
    __builtin_amdgcn_s_setprio(0);
  };

#define BAR()                                   \
  asm volatile("" ::: "memory");                \
  __builtin_amdgcn_s_barrier();                 \
  asm volatile("" ::: "memory")
#define SEAL() asm volatile("s_waitcnt vmcnt(0)" ::: "memory")

  // prologue: tile0 + tile1-A staged; vmcnt(4) -> tile0 landed; first reads.
  STGA(0); STGB(0); STGA(1);
  asm volatile("s_waitcnt vmcnt(4)" ::: "memory");
  BAR();
  RDA(0, 0); RDB(0, 0);   // R_0(0): af03,bf01 from buf0

  // Seal/WAR ledger (per tile t, phases ph0..ph3, one barrier each):
  //  buf((t+1)&1) receives A(t+1)@ph3(t-1), B(t+1)@ph0(t); sealed by
  //  SEAL@ph2(t)+BAR (in-flight then = exactly those 8 stale loads);
  //  first read of buf((t+1)&1) is R_0(t+1)@ph3(t). Stage WAR: every STG
  //  lands >=1 barrier after the last lgkm-complete read of its region.
#pragma unroll 1
  for (int u = 0; u < 16; ++u) {
    const int t = 2 * u;
    // ===== tile t (buf0) =====
    QM(0, 0);                  // uses af03,bf01 (read last phase)
    RDA(0, 4);                 // R_1: af47
    STGB(t + 1);               // B(t+1) -> buf1
    BAR();
    QM(4, 0);
    RDB(0, 2);                 // R_2: bf23
    BAR();
    QM(4, 2);
    SEAL();                    // retire A(t+1),B(t+1) -> buf1 sealed
    BAR();
    QM(0, 2);
    RDA(1, 0); RDB(1, 0);      // R_0(t+1) from buf1
    STGA(t + 2);               // A(t+2) -> buf0
    BAR();
    // ===== tile t+1 (buf1) =====
    QM(0, 0);
    RDA(1, 4);
    STGB(t + 2);               // B(t+2) -> buf0
    BAR();
    QM(4, 0);
    RDB(1, 2);
    BAR();
    QM(4, 2);
    SEAL();                    // retire A(t+2),B(t+2) -> buf0 sealed
    BAR();
    QM(0, 2);
    RDA(0, 0); RDB(0, 0);      // R_0(t+2) from buf0 (junk on last iter; dead)
    STGA(t + 3);               // A(t+3) -> buf1 (wraps to junk on last iter)
    BAR();
  }
  asm volatile("s_waitcnt vmcnt(0) lgkmcnt(0)" ::: "memory");  // drain junk
#undef BAR
#undef SEAL

  // epilogue: D rows = n (quad*4+r), cols = m (ln); [B,H,S,D] store
#pragma unroll
  for (int tn = 0; tn < 4; ++tn) {
    const int n_base = n0 + wn + tn * 16 + quad * 4;
    const f32x4 bv = *(const f32x4*)&bias[n_base];
    const int h = n_base >> 7, dl = n_base & 127;
#pragma unroll
    for (int tm = 0; tm < 8; ++tm) {
      const int m = m0 + wm + tm * 16 + ln;
      const int b = m >> 11, s = m & 2047;
      u16x4 ov;
#pragma unroll
      for (int r = 0; r < 4; ++r) ov[r] = f2bf((acc[tm][tn][r] + bv[r]) * scale);
      *(u16x4*)&out[(((size_t)(b * 16 + h)) << 18) + ((size_t)s << 7) + dl] = ov;
    }
  }
}

// ---------------- V projection GEMM (proven 128^2 core, transposed out) ----------------
__global__ __launch_bounds__(256, 2) void gemm_v(const u16* __restrict__ A,
                                                 const u16* __restrict__ Bw,
                                                 const float* __restrict__ bias,
                                                 u16* __restrict__ Vo) {
  __shared__ __align__(16) u16 smem[16384];
  u16* sA = smem;
  u16* sB = smem + 8192;
  const int tid = threadIdx.x;
  const int lane = tid & 63, w = tid >> 6;
  const int ln = lane & 15, quad = lane >> 4;
  const int m0 = blockIdx.y * 128, n0 = blockIdx.x * 128;
  const int wm = (w >> 1) * 64, wn = (w & 1) * 64;

  f32x4 acc[4][4] = {};
  gemm_core<0>(A, Bw, sA, sB, acc, m0, n0, tid);
  const int b = m0 >> 11;
#pragma unroll
  for (int tn = 0; tn < 4; ++tn) {
    const int n = n0 + wn + tn * 16 + ln;   // global d index
    const float bv = bias[n];
    const int h = n >> 7, dl = n & 127;
#pragma unroll
    for (int tm = 0; tm < 4; ++tm) {
      const int s_base = (m0 & 2047) + wm + tm * 16 + quad * 4;
      u16x4 ov;
#pragma unroll
      for (int r = 0; r < 4; ++r) ov[r] = f2bf(acc[tm][tn][r] + bv);
      *(u16x4*)&Vo[(((size_t)((b * 16 + h) * 128 + dl)) << 11) + s_base] = ov;
    }
  }
}

// ---------------- output projection GEMM (fp32 out, proven 128^2 core) ----------------
__global__ __launch_bounds__(256, 2) void gemm_out(const u16* __restrict__ A,
                                                   const u16* __restrict__ Bw,
                                                   const float* __restrict__ bias,
                                                   float* __restrict__ out) {
  __shared__ __align__(16) u16 smem[16384];
  u16* sA = smem;
  u16* sB = smem + 8192;
  const int tid = threadIdx.x;
  const int lane = tid & 63, w = tid >> 6;
  const int ln = lane & 15, quad = lane >> 4;
  const int m0 = blockIdx.y * 128, n0 = blockIdx.x * 128;
  const int wm = (w >> 1) * 64, wn = (w & 1) * 64;

  f32x4 acc[4][4] = {};
  gemm_core<1>(A, Bw, sA, sB, acc, m0, n0, tid);
#pragma unroll
  for (int tn = 0; tn < 4; ++tn) {
    const int n_base = n0 + wn + tn * 16 + quad * 4;
    const f32x4 bv = *(const f32x4*)&bias[n_base];
#pragma unroll
    for (int tm = 0; tm < 4; ++tm) {
      const int m = m0 + wm + tm * 16 + ln;
      f32x4 ov;
#pragma unroll
      for (int r = 0; r < 4; ++r) ov[r] = acc[tm][tn][r] + bv[r];
      *(f32x4*)&out[(size_t)m * 2048 + n_base] = ov;
    }
  }
}

// ---------------- causal flash attention (S^T orientation) ----------------
// Q,K: [B,H,S,D] bf16 (Q pre-scaled); Vt: [B,H,D,S] bf16. ctx: [B,S,E] bf16.
__global__ __launch_bounds__(256, 2) void attn_kernel(const u16* __restrict__ Q,
                                                      const u16* __restrict__ Kp,
                                                      const u16* __restrict__ Vt,
                                                      u16* __restrict__ ctx) {
  __shared__ __align__(16) u16 smem[24576];  // sP[8192] | sK[8192] | sV[8192]
  u16* sP = smem;
  u16* sK = smem + 8192;
  u16* sV = smem + 16384;

  const int flat = blockIdx.x + (blockIdx.y << 4);
  const int bh = flat >> 4;
  const int i = (flat < 256) ? (15 - (flat & 15)) : (flat & 15);  // pair work-balance
  const size_t base = (size_t)bh << 18;

  const int tid = threadIdx.x, lane = tid & 63, w = tid >> 6;
  const int ln = lane & 15, quad = lane >> 4, ln7 = lane & 7;

  // ---- stage Q tile (32KB) into sK..sV region, swizzled ----
#pragma unroll
  for (int c = 0; c < 8; ++c) {
    const int chunk0 = (c * 4 + w) * 64;
    const int chunk = chunk0 + lane;
    const int row = chunk >> 4, cc = chunk & 15;
    gl_lds16(Q + base + (size_t)((i * 128 + row) * 128 + ((cc ^ (row & 15)) << 3)),
             (char*)sK + chunk0 * 16);
  }
  __syncthreads();
  s16x8 qf[2][4];
#pragma unroll
  for (int qt = 0; qt < 2; ++qt)
#pragma unroll
    for (int kc = 0; kc < 4; ++kc)
      qf[qt][kc] =
          *(const s16x8*)&sK[(w * 32 + qt * 16 + ln) * 128 + (((kc * 4 + quad) ^ ln) << 3)];
  __syncthreads();

  auto stageK = [&](int j) {
#pragma unroll
    for (int c = 0; c < 4; ++c) {
      const int chunk0 = (c * 4 + w) * 64;
      const int chunk = chunk0 + lane;
      const int row = chunk >> 4, cc = chunk & 15;
      gl_lds16(Kp + base + (size_t)((j * 64 + row) * 128 + ((cc ^ (row & 15)) << 3)),
               (char*)sK + chunk0 * 16);
    }
  };
  auto stageV = [&](int j) {
#pragma unroll
    for (int c = 0; c < 4; ++c) {
      const int chunk0 = (c * 4 + w) * 64;
      const int chunk = chunk0 + lane;
      const int row = chunk >> 3, cc = chunk & 7;
      gl_lds16(Vt + base + (size_t)(row * 2048 + j * 64 + ((cc ^ (row & 7)) << 3)),
               (char*)sV + chunk0 * 16);
    }
  };

  stageK(0);
  stageV(0);
  __syncthreads();

  f32x4 o_acc[8][2] = {};
  float lsum[2] = {0.f, 0.f};
  const int jmax = 2 * i + 1;
  const int qg = i * 128 + w * 32 + ln;  // + qt*16 gives lane's global q

  for (int j = 0; j <= jmax; ++j) {
    // ---- S^T = K . Q^T (64k x 128q): A = K frags, B = Q regs ----
    f32x4 sacc[4][2] = {};
#pragma unroll
    for (int kc = 0; kc < 4; ++kc) {
      s16x8 kf[4];
#pragma unroll
      for (int kt = 0; kt < 4; ++kt)
        kf[kt] = *(const s16x8*)&sK[(kt * 16 + ln) * 128 + (((kc * 4 + quad) ^ ln) << 3)];
#pragma unroll
      for (int kt = 0; kt < 4; ++kt)
#pragma unroll
        for (int qt = 0; qt < 2; ++qt)
          sacc[kt][qt] = MFMA16(kf[kt], qf[qt][kc], sacc[kt][qt]);
    }

    // ---- exp + mask + pack P[q][k] via b64 writes (swizzle key q&14) ----
    const bool diag = (j >= 2 * i);
#pragma unroll
    for (int kt = 0; kt < 4; ++kt)
#pragma unroll
      for (int qt = 0; qt < 2; ++qt) {
        u16x4 pk;
#pragma unroll
        for (int r = 0; r < 4; ++r) {
          const int kg = j * 64 + kt * 16 + quad * 4 + r;
          float pv = __expf(sacc[kt][qt][r]);
          if (diag && kg > qg + qt * 16) pv = 0.f;
          lsum[qt] += pv;
          pk[r] = f2bf(pv);
        }
        const int qrow = w * 32 + qt * 16 + ln;
        const int c = kt * 4 + quad;
        *(u16x4*)&sP[qrow * 64 + ((c ^ (qrow & 14)) << 2)] = pk;
      }
    __syncthreads();            // A: QK reads of sK done; V(j) drained; P visible
    if (j < jmax) stageK(j + 1);

    // ---- O^T += V . P^T : A = V frags (d rows), B = P frags (q rows) ----
#pragma unroll
    for (int kc = 0; kc < 2; ++kc) {
      s16x8 vf[8], pf[2];
#pragma unroll
      for (int qt = 0; qt < 2; ++qt) {
        const int qrow = w * 32 + qt * 16 + ln;
        const int c0 = kc * 8 + quad * 2;
        pf[qt] = *(const s16x8*)&sP[qrow * 64 + ((c0 ^ (qrow & 14)) << 2)];
      }
#pragma unroll
      for (int dt = 0; dt < 8; ++dt)
        vf[dt] = *(const s16x8*)&sV[(dt * 16 + ln) * 64 + (((kc * 4 + quad) ^ ln7) << 3)];
#pragma unroll
      for (int dt = 0; dt < 8; ++dt)
#pragma unroll
        for (int qt = 0; qt < 2; ++qt)
          o_acc[dt][qt] = MFMA16(vf[dt], pf[qt], o_acc[dt][qt]);
    }
    __syncthreads();            // B: PV reads of sV done; K(j+1) drained
    if (j < jmax) stageV(j + 1);
  }

  // ---- epilogue: reduce lsum over quads, scale, u16x4 ctx stores ----
  const int b = bh >> 4, h = bh & 15;
  float rinv[2];
#pragma unroll
  for (int qt = 0; qt < 2; ++qt) {
    float s = lsum[qt];
    s += __shfl_xor(s, 16);
    s += __shfl_xor(s, 32);
    rinv[qt] = __builtin_amdgcn_rcpf(s);
  }
#pragma unroll
  for (int dt = 0; dt < 8; ++dt)
#pragma unroll
    for (int qt = 0; qt < 2; ++qt) {
      const int sg = i * 128 + w * 32 + qt * 16 + ln;
      const int d0 = h * 128 + dt * 16 + quad * 4;
      u16x4 ov;
#pragma unroll
      for (int r = 0; r < 4; ++r) ov[r] = f2bf(o_acc[dt][qt][r] * rinv[qt]);
      *(u16x4*)&ctx[((size_t)b << 22) + (size_t)sg * 2048 + d0] = ov;
    }
}

// ---------------- launch ----------------
extern "C" void kernel_launch(void* const* d_in, const int* in_sizes, int n_in,
                              void* d_out, int out_size, void* d_ws, size_t ws_size,
                              hipStream_t stream) {
  const float* x = (const float*)d_in[0];
  const float* Wq = (const float*)d_in[1];
  const float* bq = (const float*)d_in[2];
  const float* Wk = (const float*)d_in[3];
  const float* bk = (const float*)d_in[4];
  const float* Wv = (const float*)d_in[5];
  const float* bv = (const float*)d_in[6];
  const float* Wo = (const float*)d_in[7];
  const float* bo = (const float*)d_in[8];

  u16* ws = (u16*)d_ws;
  u16* xb = ws;
  u16* Wqb = xb + 8388608;
  u16* Wkb = Wqb + 4194304;
  u16* Wvb = Wkb + 4194304;
  u16* Wob = Wvb + 4194304;
  u16* Qb = Wob + 4194304;    // [B,H,S,D] (pre-scaled)
  u16* Kb = Qb + 8388608;     // [B,H,S,D]
  u16* Vtb = Kb + 8388608;    // [B,H,D,S]
  u16* ctxb = Vtb + 8388608;  // [B,S,E]

  cast6<<<dim3(4096, 6), 256, 0, stream>>>(x, Wq, Wk, Wv, Wo, ws);

  gemm_qk256<<<dim3(8, 16, 2), 512, 0, stream>>>(xb, Wqb, Wkb, bq, bk, Qb, Kb);
  gemm_v<<<dim3(16, 32), 256, 0, stream>>>(xb, Wvb, bv, Vtb);

  attn_kernel<<<dim3(16, 32), 256, 0, stream>>>(Qb, Kb, Vtb, ctxb);

  gemm_out<<<dim3(16, 32), 256, 0, stream>>>(ctxb, Wob, bo, (float*)d_out);
}

// Round 6
// 349.877 us; speedup vs baseline: 1.0581x; 1.0181x over previous
//
#include <hip/hip_runtime.h>

typedef unsigned short u16;
typedef __attribute__((ext_vector_type(4))) float f32x4;
typedef __attribute__((ext_vector_type(8))) short s16x8;
typedef __attribute__((ext_vector_type(4))) unsigned short u16x4;
typedef __attribute__((ext_vector_type(2))) unsigned u32x2;

#define MFMA16(a, b, c) __builtin_amdgcn_mfma_f32_16x16x32_bf16((a), (b), (c), 0, 0, 0)

__device__ __forceinline__ u16 f2bf(float f) {
  union { float f; unsigned u; } v; v.f = f;
  unsigned u = v.u;
  u += 0x7fffu + ((u >> 16) & 1u);   // RNE
  return (u16)(u >> 16);
}

__device__ __forceinline__ unsigned cvtpk(float a, float b) {  // lo<-a, hi<-b (RNE)
  unsigned r;
  asm("v_cvt_pk_bf16_f32 %0, %1, %2" : "=v"(r) : "v"(a), "v"(b));
  return r;
}

__device__ __forceinline__ void gl_lds16(const void* g, void* l) {
  __builtin_amdgcn_global_load_lds(
      (const __attribute__((address_space(1))) void*)g,
      (__attribute__((address_space(3))) void*)l, 16, 0, 0);
}

// ---------------- fused cast fp32 -> bf16 ----------------
__global__ void cast6(const float* __restrict__ x,
                      const float* __restrict__ w0, const float* __restrict__ w1,
                      const float* __restrict__ w2, const float* __restrict__ w3,
                      u16* __restrict__ ws) {
  const int y = blockIdx.y;
  const float* src;
  u16* dst;
  if (y < 2) { src = x + (size_t)y * 4194304; dst = ws + (size_t)y * 4194304; }
  else {
    src = (y == 2) ? w0 : (y == 3) ? w1 : (y == 4) ? w2 : w3;
    dst = ws + 8388608 + (size_t)(y - 2) * 4194304;
  }
  const int i = blockIdx.x * 256 + threadIdx.x;
  f32x4 v = ((const f32x4*)src)[i];
  u16x4 o;
#pragma unroll
  for (int e = 0; e < 4; ++e) o[e] = f2bf(v[e]);
  ((u16x4*)dst)[i] = o;
}

// ---------------- 128x128 GEMM core (proven; gemm_v + gemm_out) ----------------
template <int SWAP>
__device__ __forceinline__ void gemm_core(const u16* __restrict__ A,
                                          const u16* __restrict__ Bw,
                                          u16* sA, u16* sB,
                                          f32x4 (&acc)[4][4],
                                          int m0, int n0, int tid) {
  const int lane = tid & 63, w = tid >> 6;
  const int ln = lane & 15, quad = lane >> 4, ln7 = ln & 7;
  const int wm = (w >> 1) * 64, wn = (w & 1) * 64;
  const int srow = lane >> 3;
  const int scol = (((lane & 7) ^ srow)) * 8;

  for (int k0 = 0; k0 < 2048; k0 += 64) {
#pragma unroll
    for (int c = 0; c < 4; ++c) {
      const int chunk = c * 4 + w;
      const int row = chunk * 8 + srow;
      gl_lds16(A + (size_t)(m0 + row) * 2048 + k0 + scol, (char*)sA + chunk * 1024);
      gl_lds16(Bw + (size_t)(n0 + row) * 2048 + k0 + scol, (char*)sB + chunk * 1024);
    }
    __syncthreads();
#pragma unroll
    for (int kk = 0; kk < 64; kk += 32) {
      s16x8 af[4], bf[4];
      const int g = (kk >> 3) + quad;
#pragma unroll
      for (int t = 0; t < 4; ++t) {
        af[t] = *(const s16x8*)&sA[(wm + t * 16 + ln) * 64 + ((g ^ ln7) << 3)];
        bf[t] = *(const s16x8*)&sB[(wn + t * 16 + ln) * 64 + ((g ^ ln7) << 3)];
      }
#pragma unroll
      for (int tm = 0; tm < 4; ++tm)
#pragma unroll
        for (int tn = 0; tn < 4; ++tn)
          acc[tm][tn] = SWAP ? MFMA16(bf[tn], af[tm], acc[tm][tn])
                             : MFMA16(af[tm], bf[tn], acc[tm][tn]);
    }
    __syncthreads();
  }
}

// ---------------- 256x256 single-barrier-phase Q/K GEMM ----------------
// (unchanged from round 5 except Q scale folds log2(e) for attn's exp2 softmax)
__global__ __launch_bounds__(512, 2) void gemm_qk256(
    const u16* __restrict__ A,
    const u16* __restrict__ W0, const u16* __restrict__ W1,
    const float* __restrict__ b0, const float* __restrict__ b1,
    u16* __restrict__ Qo, u16* __restrict__ Ko) {
  __shared__ __align__(16) u16 smem[65536];   // 128 KiB
  const int z = blockIdx.z;
  const u16* Bw = z ? W1 : W0;
  const float* bias = z ? b1 : b0;
  u16* out = z ? Ko : Qo;
  const float scale = z ? 1.0f : 0.1275174306003988f;  // (1/sqrt(128))*log2(e)

  const int tid = threadIdx.x;
  const int lane = tid & 63, w = tid >> 6;
  const int ln = lane & 15, quad = lane >> 4, ln7 = lane & 7;
  const int m0 = blockIdx.y * 256, n0 = blockIdx.x * 256;
  const int wm = (w >> 2) << 7, wn = (w & 3) << 6;

  const int ci0 = tid, ci1 = 512 + tid;
  const int r0 = ci0 >> 3, c0k = ((ci0 & 7) ^ (r0 & 7)) << 3;
  const int r1 = ci1 >> 3, c1k = ((ci1 & 7) ^ (r1 & 7)) << 3;
  const int abase = (w >> 2) << 13;                                   // A half
  const int bbase = 16384 + (((w >> 1) & 1) << 13) + ((w & 1) << 12); // B half+qtr
  const int sw0 = (quad ^ ln7) << 3, sw1 = ((4 + quad) ^ ln7) << 3;

  f32x4 acc[8][4] = {};
  s16x8 af[8][2], bf[4][2];

  auto STGA = [&](int t) {
    u16* dst = smem + ((t & 1) << 15);
    const int kc = (t & 31) << 6;
    const u16* s0 = A + (size_t)(m0 + r0) * 2048 + kc + c0k;
    const u16* s1 = A + (size_t)(m0 + r1) * 2048 + kc + c1k;
    gl_lds16(s0, dst + ci0 * 8);
    gl_lds16(s1, dst + ci1 * 8);
    gl_lds16(s0 + (size_t)128 * 2048, dst + 8192 + ci0 * 8);
    gl_lds16(s1 + (size_t)128 * 2048, dst + 8192 + ci1 * 8);
  };
  auto STGB = [&](int t) {
    u16* dst = smem + ((t & 1) << 15) + 16384;
    const int kc = (t & 31) << 6;
    const u16* s0 = Bw + (size_t)(n0 + r0) * 2048 + kc + c0k;
    const u16* s1 = Bw + (size_t)(n0 + r1) * 2048 + kc + c1k;
    gl_lds16(s0, dst + ci0 * 8);
    gl_lds16(s1, dst + ci1 * 8);
    gl_lds16(s0 + (size_t)128 * 2048, dst + 8192 + ci0 * 8);
    gl_lds16(s1 + (size_t)128 * 2048, dst + 8192 + ci1 * 8);
  };
  auto RDA = [&](int buf, int tm0) {
    const u16* p = smem + (buf << 15) + abase;
#pragma unroll
    for (int u = 0; u < 4; ++u) {
      const int tt = tm0 + u;
      af[tt][0] = *(const s16x8*)&p[(tt * 16 + ln) * 64 + sw0];
      af[tt][1] = *(const s16x8*)&p[(tt * 16 + ln) * 64 + sw1];
    }
  };
  auto RDB = [&](int buf, int tn0) {
    const u16* p = smem + (buf << 15) + bbase;
#pragma unroll
    for (int u = 0; u < 2; ++u) {
      const int tt = tn0 + u;
      bf[tt][0] = *(const s16x8*)&p[(tt * 16 + ln) * 64 + sw0];
      bf[tt][1] = *(const s16x8*)&p[(tt * 16 + ln) * 64 + sw1];
    }
  };
  auto QM = [&](int tm0, int tn0) {
    __builtin_amdgcn_s_setprio(1);
#pragma unroll
    for (int tm = tm0; tm < tm0 + 4; ++tm)
#pragma unroll
      for (int tn = tn0; tn < tn0 + 2; ++tn)
#pragma unroll
        for (int ks = 0; ks < 2; ++ks)
          acc[tm][tn] = MFMA16(bf[tn][ks], af[tm][ks], acc[tm][tn]);
    __builtin_amdgcn_s_setprio(0);
  };

#define BAR()                                   \
  asm volatile("" ::: "memory");                \
  __builtin_amdgcn_s_barrier();                 \
  asm volatile("" ::: "memory")
#define SEAL() asm volatile("s_waitcnt vmcnt(0)" ::: "memory")

  STGA(0); STGB(0); STGA(1);
  asm volatile("s_waitcnt vmcnt(4)" ::: "memory");
  BAR();
  RDA(0, 0); RDB(0, 0);

#pragma unroll 1
  for (int u = 0; u < 16; ++u) {
    const int t = 2 * u;
    QM(0, 0);
    RDA(0, 4);
    STGB(t + 1);
    BAR();
    QM(4, 0);
    RDB(0, 2);
    BAR();
    QM(4, 2);
    SEAL();
    BAR();
    QM(0, 2);
    RDA(1, 0); RDB(1, 0);
    STGA(t + 2);
    BAR();
    QM(0, 0);
    RDA(1, 4);
    STGB(t + 2);
    BAR();
    QM(4, 0);
    RDB(1, 2);
    BAR();
    QM(4, 2);
    SEAL();
    BAR();
    QM(0, 2);
    RDA(0, 0); RDB(0, 0);
    STGA(t + 3);
    BAR();
  }
  asm volatile("s_waitcnt vmcnt(0) lgkmcnt(0)" ::: "memory");
#undef BAR
#undef SEAL

#pragma unroll
  for (int tn = 0; tn < 4; ++tn) {
    const int n_base = n0 + wn + tn * 16 + quad * 4;
    const f32x4 bv = *(const f32x4*)&bias[n_base];
    const int h = n_base >> 7, dl = n_base & 127;
#pragma unroll
    for (int tm = 0; tm < 8; ++tm) {
      const int m = m0 + wm + tm * 16 + ln;
      const int b = m >> 11, s = m & 2047;
      u16x4 ov;
#pragma unroll
      for (int r = 0; r < 4; ++r) ov[r] = f2bf((acc[tm][tn][r] + bv[r]) * scale);
      *(u16x4*)&out[(((size_t)(b * 16 + h)) << 18) + ((size_t)s << 7) + dl] = ov;
    }
  }
}

// ---------------- V projection GEMM (proven 128^2 core, transposed out) ----------------
__global__ __launch_bounds__(256, 2) void gemm_v(const u16* __restrict__ A,
                                                 const u16* __restrict__ Bw,
                                                 const float* __restrict__ bias,
                                                 u16* __restrict__ Vo) {
  __shared__ __align__(16) u16 smem[16384];
  u16* sA = smem;
  u16* sB = smem + 8192;
  const int tid = threadIdx.x;
  const int lane = tid & 63, w = tid >> 6;
  const int ln = lane & 15, quad = lane >> 4;
  const int m0 = blockIdx.y * 128, n0 = blockIdx.x * 128;
  const int wm = (w >> 1) * 64, wn = (w & 1) * 64;

  f32x4 acc[4][4] = {};
  gemm_core<0>(A, Bw, sA, sB, acc, m0, n0, tid);
  const int b = m0 >> 11;
#pragma unroll
  for (int tn = 0; tn < 4; ++tn) {
    const int n = n0 + wn + tn * 16 + ln;   // global d index
    const float bv = bias[n];
    const int h = n >> 7, dl = n & 127;
#pragma unroll
    for (int tm = 0; tm < 4; ++tm) {
      const int s_base = (m0 & 2047) + wm + tm * 16 + quad * 4;
      u16x4 ov;
#pragma unroll
      for (int r = 0; r < 4; ++r) ov[r] = f2bf(acc[tm][tn][r] + bv);
      *(u16x4*)&Vo[(((size_t)((b * 16 + h) * 128 + dl)) << 11) + s_base] = ov;
    }
  }
}

// ---------------- output projection GEMM (fp32 out, proven 128^2 core) ----------------
__global__ __launch_bounds__(256, 2) void gemm_out(const u16* __restrict__ A,
                                                   const u16* __restrict__ Bw,
                                                   const float* __restrict__ bias,
                                                   float* __restrict__ out) {
  __shared__ __align__(16) u16 smem[16384];
  u16* sA = smem;
  u16* sB = smem + 8192;
  const int tid = threadIdx.x;
  const int lane = tid & 63, w = tid >> 6;
  const int ln = lane & 15, quad = lane >> 4;
  const int m0 = blockIdx.y * 128, n0 = blockIdx.x * 128;
  const int wm = (w >> 1) * 64, wn = (w & 1) * 64;

  f32x4 acc[4][4] = {};
  gemm_core<1>(A, Bw, sA, sB, acc, m0, n0, tid);
#pragma unroll
  for (int tn = 0; tn < 4; ++tn) {
    const int n_base = n0 + wn + tn * 16 + quad * 4;
    const f32x4 bv = *(const f32x4*)&bias[n_base];
#pragma unroll
    for (int tm = 0; tm < 4; ++tm) {
      const int m = m0 + wm + tm * 16 + ln;
      f32x4 ov;
#pragma unroll
      for (int r = 0; r < 4; ++r) ov[r] = acc[tm][tn][r] + bv[r];
      *(f32x4*)&out[(size_t)m * 2048 + n_base] = ov;
    }
  }
}

// ---------------- causal flash attention (S^T, dbuf K/V, 1 barrier/tile) ----
// Q,K: [B,H,S,D] bf16 (Q pre-scaled by (1/sqrt(D))*log2(e)); Vt: [B,H,D,S].
// LDS 80KB: sP[16K] | sK0|sK1 [16K each... 8192 u16] | sV0|sV1. 2 blocks/CU.
// Per KV-tile: stage(j+1 -> buf^1) first, compute QK/SM/PV from buf, ONE
// syncthreads at end (seals buf WAR + drains j+1 loads that had the whole
// body to land). sP is wave-private (rows w*32..+31): write->read needs only
// per-wave lgkmcnt(0) + sched_barrier, no block barrier.
__global__ __launch_bounds__(256, 2) void attn_kernel(const u16* __restrict__ Q,
                                                      const u16* __restrict__ Kp,
                                                      const u16* __restrict__ Vt,
                                                      u16* __restrict__ ctx) {
  __shared__ __align__(16) u16 smem[40960];  // 80 KiB
  u16* sP = smem;                            // 128 x 64
  // sK buf b: smem + 8192 + b*8192 (64 x 128); sV buf b: smem + 24576 + b*8192 (128 x 64)

  const int flat = blockIdx.x + (blockIdx.y << 4);
  const int bh = flat >> 4;
  const int i = (flat < 256) ? (15 - (flat & 15)) : (flat & 15);  // pair work-balance
  const size_t base = (size_t)bh << 18;

  const int tid = threadIdx.x, lane = tid & 63, w = tid >> 6;
  const int ln = lane & 15, quad = lane >> 4, ln7 = lane & 7;

  // ---- stage Q tile (32KB) into sK0..sK1 region, swizzled ----
#pragma unroll
  for (int c = 0; c < 8; ++c) {
    const int chunk0 = (c * 4 + w) * 64;
    const int chunk = chunk0 + lane;
    const int row = chunk >> 4, cc = chunk & 15;
    gl_lds16(Q + base + (size_t)((i * 128 + row) * 128 + ((cc ^ (row & 15)) << 3)),
             (char*)(smem + 8192) + chunk0 * 16);
  }
  __syncthreads();
  s16x8 qf[2][4];
#pragma unroll
  for (int qt = 0; qt < 2; ++qt)
#pragma unroll
    for (int kc = 0; kc < 4; ++kc)
      qf[qt][kc] = *(const s16x8*)&smem[8192 + (w * 32 + qt * 16 + ln) * 128 +
                                        (((kc * 4 + quad) ^ ln) << 3)];
  __syncthreads();   // all waves done reading Q region

  auto stageK = [&](int j, int buf) {
    u16* dst = smem + 8192 + buf * 8192;
#pragma unroll
    for (int c = 0; c < 4; ++c) {
      const int chunk0 = (c * 4 + w) * 64;
      const int chunk = chunk0 + lane;
      const int row = chunk >> 4, cc = chunk & 15;
      gl_lds16(Kp + base + (size_t)((j * 64 + row) * 128 + ((cc ^ (row & 15)) << 3)),
               (char*)dst + chunk0 * 16);
    }
  };
  auto stageV = [&](int j, int buf) {
    u16* dst = smem + 24576 + buf * 8192;
#pragma unroll
    for (int c = 0; c < 4; ++c) {
      const int chunk0 = (c * 4 + w) * 64;
      const int chunk = chunk0 + lane;
      const int row = chunk >> 3, cc = chunk & 7;
      gl_lds16(Vt + base + (size_t)(row * 2048 + j * 64 + ((cc ^ (row & 7)) << 3)),
               (char*)dst + chunk0 * 16);
    }
  };

  stageK(0, 0);
  stageV(0, 0);
  __syncthreads();   // tile 0 landed (cold-start latency paid once)

  f32x4 o_acc[8][2] = {};
  float lsum[2] = {0.f, 0.f};
  const int jmax = 2 * i + 1;
  const int qg = i * 128 + w * 32 + ln;  // + qt*16 gives lane's global q

  for (int j = 0; j <= jmax; ++j) {
    const int cb = j & 1;
    if (j < jmax) { stageK(j + 1, cb ^ 1); stageV(j + 1, cb ^ 1); }
    const u16* sK = smem + 8192 + cb * 8192;
    const u16* sV = smem + 24576 + cb * 8192;

    // ---- S^T = K . Q^T (64k x 128q): A = K frags, B = Q regs ----
    f32x4 sacc[4][2] = {};
#pragma unroll
    for (int kc = 0; kc < 4; ++kc) {
      s16x8 kf[4];
#pragma unroll
      for (int kt = 0; kt < 4; ++kt)
        kf[kt] = *(const s16x8*)&sK[(kt * 16 + ln) * 128 + (((kc * 4 + quad) ^ ln) << 3)];
#pragma unroll
      for (int kt = 0; kt < 4; ++kt)
#pragma unroll
        for (int qt = 0; qt < 2; ++qt)
          sacc[kt][qt] = MFMA16(kf[kt], qf[qt][kc], sacc[kt][qt]);
    }

    // ---- exp2 + mask + cvt_pk pack P[q][k] (b64 writes, swizzle q&14) ----
    const bool diag = (j >= 2 * i);
#pragma unroll
    for (int kt = 0; kt < 4; ++kt)
#pragma unroll
      for (int qt = 0; qt < 2; ++qt) {
        f32x4 pv;
#pragma unroll
        for (int r = 0; r < 4; ++r) {
          float p = __builtin_amdgcn_exp2f(sacc[kt][qt][r]);
          const int kg = j * 64 + kt * 16 + quad * 4 + r;
          if (diag && kg > qg + qt * 16) p = 0.f;
          lsum[qt] += p;
          pv[r] = p;
        }
        u32x2 pk2;
        pk2[0] = cvtpk(pv[0], pv[1]);
        pk2[1] = cvtpk(pv[2], pv[3]);
        const int qrow = w * 32 + qt * 16 + ln;
        const int c = kt * 4 + quad;
        *(u32x2*)&sP[qrow * 64 + ((c ^ (qrow & 14)) << 2)] = pk2;
      }
    // sP is wave-private: per-wave seal of the 8 ds_writes is sufficient.
    asm volatile("s_waitcnt lgkmcnt(0)" ::: "memory");
    __builtin_amdgcn_sched_barrier(0);

    // ---- O^T += V . P^T : A = V frags (d rows), B = P frags (q rows) ----
#pragma unroll
    for (int kc = 0; kc < 2; ++kc) {
      s16x8 vf[8], pf[2];
#pragma unroll
      for (int qt = 0; qt < 2; ++qt) {
        const int qrow = w * 32 + qt * 16 + ln;
        const int c0 = kc * 8 + quad * 2;
        pf[qt] = *(const s16x8*)&sP[qrow * 64 + ((c0 ^ (qrow & 14)) << 2)];
      }
#pragma unroll
      for (int dt = 0; dt < 8; ++dt)
        vf[dt] = *(const s16x8*)&sV[(dt * 16 + ln) * 64 + (((kc * 4 + quad) ^ ln7) << 3)];
#pragma unroll
      for (int dt = 0; dt < 8; ++dt)
#pragma unroll
        for (int qt = 0; qt < 2; ++qt)
          o_acc[dt][qt] = MFMA16(vf[dt], pf[qt], o_acc[dt][qt]);
    }
    __syncthreads();  // seals buf[cb] reads (WAR for j+2) + drains j+1 stages
  }

  // ---- epilogue: reduce lsum over quads, scale, u16x4 ctx stores ----
  const int b = bh >> 4, h = bh & 15;
  float rinv[2];
#pragma unroll
  for (int qt = 0; qt < 2; ++qt) {
    float s = lsum[qt];
    s += __shfl_xor(s, 16);
    s += __shfl_xor(s, 32);
    rinv[qt] = __builtin_amdgcn_rcpf(s);
  }
#pragma unroll
  for (int dt = 0; dt < 8; ++dt)
#pragma unroll
    for (int qt = 0; qt < 2; ++qt) {
      const int sg = i * 128 + w * 32 + qt * 16 + ln;
      const int d0 = h * 128 + dt * 16 + quad * 4;
      u16x4 ov;
#pragma unroll
      for (int r = 0; r < 4; ++r) ov[r] = f2bf(o_acc[dt][qt][r] * rinv[qt]);
      *(u16x4*)&ctx[((size_t)b << 22) + (size_t)sg * 2048 + d0] = ov;
    }
}

// ---------------- launch ----------------
extern "C" void kernel_launch(void* const* d_in, const int* in_sizes, int n_in,
                              void* d_out, int out_size, void* d_ws, size_t ws_size,
                              hipStream_t stream) {
  const float* x = (const float*)d_in[0];
  const float* Wq = (const float*)d_in[1];
  const float* bq = (const float*)d_in[2];
  const float* Wk = (const float*)d_in[3];
  const float* bk = (const float*)d_in[4];
  const float* Wv = (const float*)d_in[5];
  const float* bv = (const float*)d_in[6];
  const float* Wo = (const float*)d_in[7];
  const float* bo = (const float*)d_in[8];

  u16* ws = (u16*)d_ws;
  u16* xb = ws;
  u16* Wqb = xb + 8388608;
  u16* Wkb = Wqb + 4194304;
  u16* Wvb = Wkb + 4194304;
  u16* Wob = Wvb + 4194304;
  u16* Qb = Wob + 4194304;    // [B,H,S,D] (pre-scaled w/ log2e fold)
  u16* Kb = Qb + 8388608;     // [B,H,S,D]
  u16* Vtb = Kb + 8388608;    // [B,H,D,S]
  u16* ctxb = Vtb + 8388608;  // [B,S,E]

  cast6<<<dim3(4096, 6), 256, 0, stream>>>(x, Wq, Wk, Wv, Wo, ws);

  gemm_qk256<<<dim3(8, 16, 2), 512, 0, stream>>>(xb, Wqb, Wkb, bq, bk, Qb, Kb);
  gemm_v<<<dim3(16, 32), 256, 0, stream>>>(xb, Wvb, bv, Vtb);

  attn_kernel<<<dim3(16, 32), 256, 0, stream>>>(Qb, Kb, Vtb, ctxb);

  gemm_out<<<dim3(16, 32), 256, 0, stream>>>(ctxb, Wob, bo, (float*)d_out);
}

// Round 8
// 339.891 us; speedup vs baseline: 1.0891x; 1.0294x over previous
//
#include <hip/hip_runtime.h>

typedef unsigned short u16;
typedef __attribute__((ext_vector_type(4))) float f32x4;
typedef __attribute__((ext_vector_type(8))) short s16x8;
typedef __attribute__((ext_vector_type(4))) unsigned short u16x4;
typedef __attribute__((ext_vector_type(2))) unsigned u32x2;

#define MFMA16(a, b, c) __builtin_amdgcn_mfma_f32_16x16x32_bf16((a), (b), (c), 0, 0, 0)

__device__ __forceinline__ u16 f2bf(float f) {
  union { float f; unsigned u; } v; v.f = f;
  unsigned u = v.u;
  u += 0x7fffu + ((u >> 16) & 1u);   // RNE
  return (u16)(u >> 16);
}

__device__ __forceinline__ unsigned cvtpk(float a, float b) {  // lo<-a, hi<-b (RNE)
  unsigned r;
  asm("v_cvt_pk_bf16_f32 %0, %1, %2" : "=v"(r) : "v"(a), "v"(b));
  return r;
}

__device__ __forceinline__ void gl_lds16(const void* g, void* l) {
  __builtin_amdgcn_global_load_lds(
      (const __attribute__((address_space(1))) void*)g,
      (__attribute__((address_space(3))) void*)l, 16, 0, 0);
}

#define BARF()                                  \
  asm volatile("" ::: "memory");                \
  __builtin_amdgcn_s_barrier();                 \
  asm volatile("" ::: "memory")

// ---------------- fused cast fp32 -> bf16 ----------------
__global__ void cast6(const float* __restrict__ x,
                      const float* __restrict__ w0, const float* __restrict__ w1,
                      const float* __restrict__ w2, const float* __restrict__ w3,
                      u16* __restrict__ ws) {
  const int y = blockIdx.y;
  const float* src;
  u16* dst;
  if (y < 2) { src = x + (size_t)y * 4194304; dst = ws + (size_t)y * 4194304; }
  else {
    src = (y == 2) ? w0 : (y == 3) ? w1 : (y == 4) ? w2 : w3;
    dst = ws + 8388608 + (size_t)(y - 2) * 4194304;
  }
  const int i = blockIdx.x * 256 + threadIdx.x;
  f32x4 v = ((const f32x4*)src)[i];
  u16x4 o;
#pragma unroll
  for (int e = 0; e < 4; ++e) o[e] = f2bf(v[e]);
  ((u16x4*)dst)[i] = o;
}

// ---------------- 256x256 1-barrier/K-tile Q/K GEMM ----------------
// 8 waves (2M x 4N), per-wave 128x64; 24 ds_read_b128 / 64 MFMA per K-tile.
// LDS 128 KiB = 2 buf x {A 256x64 | B 256x64}, rows linear, src-col XOR
// pre-swizzle. One barrier per K-tile: {vmcnt(0) [stage(t) is one body old
// -> cheap]; barrier [seals buf^1 readers + makes stage(t) cross-wave
// visible]; stage(t+1 -> buf^1); reads; MFMA}. Compiler schedules reads
// under MFMAs (all frag regs distinct; no intra-tile barriers).
__global__ __launch_bounds__(512, 2) void gemm_qk256(
    const u16* __restrict__ A,
    const u16* __restrict__ W0, const u16* __restrict__ W1,
    const float* __restrict__ b0, const float* __restrict__ b1,
    u16* __restrict__ Qo, u16* __restrict__ Ko) {
  __shared__ __align__(16) u16 smem[65536];   // 128 KiB
  const int z = blockIdx.z;
  const u16* Bw = z ? W1 : W0;
  const float* bias = z ? b1 : b0;
  u16* out = z ? Ko : Qo;
  const float scale = z ? 1.0f : 0.1275174306003988f;  // (1/sqrt(128))*log2(e)

  const int tid = threadIdx.x;
  const int lane = tid & 63, w = tid >> 6;
  const int ln = lane & 15, quad = lane >> 4, ln7 = lane & 7;
  const int m0 = blockIdx.y * 256, n0 = blockIdx.x * 256;
  const int wm = (w >> 2) << 7, wn = (w & 3) << 6;

  const int r0 = tid >> 3;                        // staged row (per 64-row group)
  const int ck = ((tid & 7) ^ (r0 & 7)) << 3;     // pre-swizzled src k-chunk
  const int abase = wm * 64;                      // A rows linear 0..255
  const int bbase = 16384 + wn * 64;              // B rows linear 0..255
  const int sw0 = (quad ^ ln7) << 3, sw1 = ((4 + quad) ^ ln7) << 3;

  f32x4 acc[8][4] = {};
  s16x8 af[8][2], bf[4][2];

  auto STGA = [&](int t) {  // 4 loads: rows r0, 64+, 128+, 192+
    u16* dst = smem + ((t & 1) << 15);
    const int kc = t << 6;
    const u16* s0 = A + (size_t)(m0 + r0) * 2048 + kc + ck;
#pragma unroll
    for (int g = 0; g < 4; ++g)
      gl_lds16(s0 + (size_t)(g * 64) * 2048, dst + g * 4096 + tid * 8);
  };
  auto STGB = [&](int t) {
    u16* dst = smem + ((t & 1) << 15) + 16384;
    const int kc = t << 6;
    const u16* s0 = Bw + (size_t)(n0 + r0) * 2048 + kc + ck;
#pragma unroll
    for (int g = 0; g < 4; ++g)
      gl_lds16(s0 + (size_t)(g * 64) * 2048, dst + g * 4096 + tid * 8);
  };
  auto RDA = [&](int buf, int tm0) {  // 4 frags x 2 ks = 8 reads
    const u16* p = smem + (buf << 15) + abase;
#pragma unroll
    for (int u = 0; u < 4; ++u) {
      const int tt = tm0 + u;
      af[tt][0] = *(const s16x8*)&p[(tt * 16 + ln) * 64 + sw0];
      af[tt][1] = *(const s16x8*)&p[(tt * 16 + ln) * 64 + sw1];
    }
  };
  auto RDB = [&](int buf, int tn0) {  // 2 frags x 2 ks = 4 reads
    const u16* p = smem + (buf << 15) + bbase;
#pragma unroll
    for (int u = 0; u < 2; ++u) {
      const int tt = tn0 + u;
      bf[tt][0] = *(const s16x8*)&p[(tt * 16 + ln) * 64 + sw0];
      bf[tt][1] = *(const s16x8*)&p[(tt * 16 + ln) * 64 + sw1];
    }
  };
  auto QM = [&](int tm0, int tn0) {  // 16 MFMA (one C-quadrant)
    __builtin_amdgcn_s_setprio(1);
#pragma unroll
    for (int tm = tm0; tm < tm0 + 4; ++tm)
#pragma unroll
      for (int tn = tn0; tn < tn0 + 2; ++tn)
#pragma unroll
        for (int ks = 0; ks < 2; ++ks)
          acc[tm][tn] = MFMA16(bf[tn][ks], af[tm][ks], acc[tm][tn]);
    __builtin_amdgcn_s_setprio(0);
  };

  STGA(0); STGB(0);
#pragma unroll 1
  for (int t = 0; t < 32; ++t) {
    const int cb = t & 1;
    asm volatile("s_waitcnt vmcnt(0)" ::: "memory");  // stage(t) landed (1 body old)
    BARF();                                           // cross-wave + seal buf^1 readers
    if (t < 31) { STGA(t + 1); STGB(t + 1); }
    RDA(cb, 0); RDB(cb, 0);
    QM(0, 0);
    RDA(cb, 4);
    QM(4, 0);
    RDB(cb, 2);
    QM(4, 2);
    QM(0, 2);
  }
  asm volatile("s_waitcnt vmcnt(0) lgkmcnt(0)" ::: "memory");

  // epilogue: D rows = n (quad*4+r), cols = m (ln); [B,H,S,D] store
#pragma unroll
  for (int tn = 0; tn < 4; ++tn) {
    const int n_base = n0 + wn + tn * 16 + quad * 4;
    const f32x4 bv = *(const f32x4*)&bias[n_base];
    const int h = n_base >> 7, dl = n_base & 127;
#pragma unroll
    for (int tm = 0; tm < 8; ++tm) {
      const int m = m0 + wm + tm * 16 + ln;
      const int b = m >> 11, s = m & 2047;
      u16x4 ov;
#pragma unroll
      for (int r = 0; r < 4; ++r) ov[r] = f2bf((acc[tm][tn][r] + bv[r]) * scale);
      *(u16x4*)&out[(((size_t)(b * 16 + h)) << 18) + ((size_t)s << 7) + dl] = ov;
    }
  }
}

// ---------------- 256x128 1-barrier/K-tile core (gemm_v / gemm_out) ----------
// 8 waves (4M x 2N), per-wave 64x64; 16 reads / 32 MFMA per K-tile.
// LDS 96 KiB = 2 buf x {A 256x64 (32K) | B 128x64 (16K)}; same swizzle and
// barrier discipline as gemm_qk256.
template <int SWAP>
__device__ __forceinline__ void gemm1b_n128(const u16* __restrict__ A,
                                            const u16* __restrict__ Bw,
                                            u16* smem, f32x4 (&acc)[4][4],
                                            int m0, int n0, int tid) {
  const int lane = tid & 63, w = tid >> 6;
  const int ln = lane & 15, quad = lane >> 4, ln7 = lane & 7;
  const int wm = (w >> 1) * 64, wn = (w & 1) * 64;
  const int r0 = tid >> 3;
  const int ck = ((tid & 7) ^ (r0 & 7)) << 3;
  const int sw0 = (quad ^ ln7) << 3, sw1 = ((4 + quad) ^ ln7) << 3;

  s16x8 af[4][2], bf[4][2];

  auto STG = [&](int t) {  // A: 4 loads (rows 0..255), B: 2 loads (rows 0..127)
    u16* dst = smem + (t & 1) * 24576;
    const int kc = t << 6;
    const u16* sa = A + (size_t)(m0 + r0) * 2048 + kc + ck;
#pragma unroll
    for (int g = 0; g < 4; ++g)
      gl_lds16(sa + (size_t)(g * 64) * 2048, dst + g * 4096 + tid * 8);
    const u16* sb = Bw + (size_t)(n0 + r0) * 2048 + kc + ck;
#pragma unroll
    for (int g = 0; g < 2; ++g)
      gl_lds16(sb + (size_t)(g * 64) * 2048, dst + 16384 + g * 4096 + tid * 8);
  };
  auto RD = [&](int buf) {  // 16 reads
    const u16* pa = smem + buf * 24576 + wm * 64;
    const u16* pb = smem + buf * 24576 + 16384 + wn * 64;
#pragma unroll
    for (int tt = 0; tt < 4; ++tt) {
      af[tt][0] = *(const s16x8*)&pa[(tt * 16 + ln) * 64 + sw0];
      af[tt][1] = *(const s16x8*)&pa[(tt * 16 + ln) * 64 + sw1];
      bf[tt][0] = *(const s16x8*)&pb[(tt * 16 + ln) * 64 + sw0];
      bf[tt][1] = *(const s16x8*)&pb[(tt * 16 + ln) * 64 + sw1];
    }
  };

  STG(0);
#pragma unroll 1
  for (int t = 0; t < 32; ++t) {
    asm volatile("s_waitcnt vmcnt(0)" ::: "memory");
    BARF();
    if (t < 31) STG(t + 1);
    RD(t & 1);
    __builtin_amdgcn_s_setprio(1);
#pragma unroll
    for (int tm = 0; tm < 4; ++tm)
#pragma unroll
      for (int tn = 0; tn < 4; ++tn)
#pragma unroll
        for (int ks = 0; ks < 2; ++ks)
          acc[tm][tn] = SWAP ? MFMA16(bf[tn][ks], af[tm][ks], acc[tm][tn])
                             : MFMA16(af[tm][ks], bf[tn][ks], acc[tm][tn]);
    __builtin_amdgcn_s_setprio(0);
  }
  asm volatile("s_waitcnt vmcnt(0) lgkmcnt(0)" ::: "memory");
}

// ---------------- V projection GEMM (transposed out) ----------------
__global__ __launch_bounds__(512, 2) void gemm_v(const u16* __restrict__ A,
                                                 const u16* __restrict__ Bw,
                                                 const float* __restrict__ bias,
                                                 u16* __restrict__ Vo) {
  __shared__ __align__(16) u16 smem[49152];  // 96 KiB
  const int tid = threadIdx.x;
  const int lane = tid & 63, w = tid >> 6;
  const int ln = lane & 15, quad = lane >> 4;
  const int m0 = blockIdx.y * 256, n0 = blockIdx.x * 128;
  const int wm = (w >> 1) * 64, wn = (w & 1) * 64;

  f32x4 acc[4][4] = {};
  gemm1b_n128<0>(A, Bw, smem, acc, m0, n0, tid);
  const int b = m0 >> 11;
#pragma unroll
  for (int tn = 0; tn < 4; ++tn) {
    const int n = n0 + wn + tn * 16 + ln;   // global d index
    const float bv = bias[n];
    const int h = n >> 7, dl = n & 127;
#pragma unroll
    for (int tm = 0; tm < 4; ++tm) {
      const int s_base = (m0 & 2047) + wm + tm * 16 + quad * 4;
      u16x4 ov;
#pragma unroll
      for (int r = 0; r < 4; ++r) ov[r] = f2bf(acc[tm][tn][r] + bv);
      *(u16x4*)&Vo[(((size_t)((b * 16 + h) * 128 + dl)) << 11) + s_base] = ov;
    }
  }
}

// ---------------- output projection GEMM (fp32 out) ----------------
__global__ __launch_bounds__(512, 2) void gemm_out(const u16* __restrict__ A,
                                                   const u16* __restrict__ Bw,
                                                   const float* __restrict__ bias,
                                                   float* __restrict__ out) {
  __shared__ __align__(16) u16 smem[49152];  // 96 KiB
  const int tid = threadIdx.x;
  const int lane = tid & 63, w = tid >> 6;
  const int ln = lane & 15, quad = lane >> 4;
  const int m0 = blockIdx.y * 256, n0 = blockIdx.x * 128;
  const int wm = (w >> 1) * 64, wn = (w & 1) * 64;

  f32x4 acc[4][4] = {};
  gemm1b_n128<1>(A, Bw, smem, acc, m0, n0, tid);
#pragma unroll
  for (int tn = 0; tn < 4; ++tn) {
    const int n_base = n0 + wn + tn * 16 + quad * 4;
    const f32x4 bv = *(const f32x4*)&bias[n_base];
#pragma unroll
    for (int tm = 0; tm < 4; ++tm) {
      const int m = m0 + wm + tm * 16 + ln;
      f32x4 ov;
#pragma unroll
      for (int r = 0; r < 4; ++r) ov[r] = acc[tm][tn][r] + bv[r];
      *(f32x4*)&out[(size_t)m * 2048 + n_base] = ov;
    }
  }
}

// ---------------- causal flash attention (S^T, dbuf K/V, 1 barrier/tile) ----
// Q,K: [B,H,S,D] bf16 (Q pre-scaled by (1/sqrt(D))*log2(e)); Vt: [B,H,D,S].
// LDS 80KB: sP[16K] | sK0|sK1 | sV0|sV1. 2 blocks/CU.
__global__ __launch_bounds__(256, 2) void attn_kernel(const u16* __restrict__ Q,
                                                      const u16* __restrict__ Kp,
                                                      const u16* __restrict__ Vt,
                                                      u16* __restrict__ ctx) {
  __shared__ __align__(16) u16 smem[40960];  // 80 KiB
  u16* sP = smem;                            // 128 x 64

  const int flat = blockIdx.x + (blockIdx.y << 4);
  const int bh = flat >> 4;
  const int i = (flat < 256) ? (15 - (flat & 15)) : (flat & 15);  // pair work-balance
  const size_t base = (size_t)bh << 18;

  const int tid = threadIdx.x, lane = tid & 63, w = tid >> 6;
  const int ln = lane & 15, quad = lane >> 4, ln7 = lane & 7;

  // ---- stage Q tile (32KB) into sK0..sK1 region, swizzled ----
#pragma unroll
  for (int c = 0; c < 8; ++c) {
    const int chunk0 = (c * 4 + w) * 64;
    const int chunk = chunk0 + lane;
    const int row = chunk >> 4, cc = chunk & 15;
    gl_lds16(Q + base + (size_t)((i * 128 + row) * 128 + ((cc ^ (row & 15)) << 3)),
             (char*)(smem + 8192) + chunk0 * 16);
  }
  __syncthreads();
  s16x8 qf[2][4];
#pragma unroll
  for (int qt = 0; qt < 2; ++qt)
#pragma unroll
    for (int kc = 0; kc < 4; ++kc)
      qf[qt][kc] = *(const s16x8*)&smem[8192 + (w * 32 + qt * 16 + ln) * 128 +
                                        (((kc * 4 + quad) ^ ln) << 3)];
  __syncthreads();   // all waves done reading Q region

  auto stageK = [&](int j, int buf) {
    u16* dst = smem + 8192 + buf * 8192;
#pragma unroll
    for (int c = 0; c < 4; ++c) {
      const int chunk0 = (c * 4 + w) * 64;
      const int chunk = chunk0 + lane;
      const int row = chunk >> 4, cc = chunk & 15;
      gl_lds16(Kp + base + (size_t)((j * 64 + row) * 128 + ((cc ^ (row & 15)) << 3)),
               (char*)dst + chunk0 * 16);
    }
  };
  auto stageV = [&](int j, int buf) {
    u16* dst = smem + 24576 + buf * 8192;
#pragma unroll
    for (int c = 0; c < 4; ++c) {
      const int chunk0 = (c * 4 + w) * 64;
      const int chunk = chunk0 + lane;
      const int row = chunk >> 3, cc = chunk & 7;
      gl_lds16(Vt + base + (size_t)(row * 2048 + j * 64 + ((cc ^ (row & 7)) << 3)),
               (char*)dst + chunk0 * 16);
    }
  };

  stageK(0, 0);
  stageV(0, 0);
  __syncthreads();   // tile 0 landed (cold-start latency paid once)

  f32x4 o_acc[8][2] = {};
  float lsum[2] = {0.f, 0.f};
  const int jmax = 2 * i + 1;
  const int qg = i * 128 + w * 32 + ln;  // + qt*16 gives lane's global q

  for (int j = 0; j <= jmax; ++j) {
    const int cb = j & 1;
    if (j < jmax) { stageK(j + 1, cb ^ 1); stageV(j + 1, cb ^ 1); }
    const u16* sK = smem + 8192 + cb * 8192;
    const u16* sV = smem + 24576 + cb * 8192;

    // ---- S^T = K . Q^T (64k x 128q): A = K frags, B = Q regs ----
    f32x4 sacc[4][2] = {};
#pragma unroll
    for (int kc = 0; kc < 4; ++kc) {
      s16x8 kf[4];
#pragma unroll
      for (int kt = 0; kt < 4; ++kt)
        kf[kt] = *(const s16x8*)&sK[(kt * 16 + ln) * 128 + (((kc * 4 + quad) ^ ln) << 3)];
#pragma unroll
      for (int kt = 0; kt < 4; ++kt)
#pragma unroll
        for (int qt = 0; qt < 2; ++qt)
          sacc[kt][qt] = MFMA16(kf[kt], qf[qt][kc], sacc[kt][qt]);
    }

    // ---- exp2 + mask + cvt_pk pack P[q][k] (b64 writes, swizzle q&14) ----
    const bool diag = (j >= 2 * i);
#pragma unroll
    for (int kt = 0; kt < 4; ++kt)
#pragma unroll
      for (int qt = 0; qt < 2; ++qt) {
        f32x4 pv;
#pragma unroll
        for (int r = 0; r < 4; ++r) {
          float p = __builtin_amdgcn_exp2f(sacc[kt][qt][r]);
          const int kg = j * 64 + kt * 16 + quad * 4 + r;
          if (diag && kg > qg + qt * 16) p = 0.f;
          lsum[qt] += p;
          pv[r] = p;
        }
        u32x2 pk2;
        pk2[0] = cvtpk(pv[0], pv[1]);
        pk2[1] = cvtpk(pv[2], pv[3]);
        const int qrow = w * 32 + qt * 16 + ln;
        const int c = kt * 4 + quad;
        *(u32x2*)&sP[qrow * 64 + ((c ^ (qrow & 14)) << 2)] = pk2;
      }
    // sP is wave-private: per-wave seal of the 8 ds_writes is sufficient.
    asm volatile("s_waitcnt lgkmcnt(0)" ::: "memory");
    __builtin_amdgcn_sched_barrier(0);

    // ---- O^T += V . P^T : A = V frags (d rows), B = P frags (q rows) ----
#pragma unroll
    for (int kc = 0; kc < 2; ++kc) {
      s16x8 vf[8], pf[2];
#pragma unroll
      for (int qt = 0; qt < 2; ++qt) {
        const int qrow = w * 32 + qt * 16 + ln;
        const int c0 = kc * 8 + quad * 2;
        pf[qt] = *(const s16x8*)&sP[qrow * 64 + ((c0 ^ (qrow & 14)) << 2)];
      }
#pragma unroll
      for (int dt = 0; dt < 8; ++dt)
        vf[dt] = *(const s16x8*)&sV[(dt * 16 + ln) * 64 + (((kc * 4 + quad) ^ ln7) << 3)];
#pragma unroll
      for (int dt = 0; dt < 8; ++dt)
#pragma unroll
        for (int qt = 0; qt < 2; ++qt)
          o_acc[dt][qt] = MFMA16(vf[dt], pf[qt], o_acc[dt][qt]);
    }
    __syncthreads();  // seals buf[cb] reads (WAR for j+2) + drains j+1 stages
  }

  // ---- epilogue: reduce lsum over quads, scale, u16x4 ctx stores ----
  const int b = bh >> 4, h = bh & 15;
  float rinv[2];
#pragma unroll
  for (int qt = 0; qt < 2; ++qt) {
    float s = lsum[qt];
    s += __shfl_xor(s, 16);
    s += __shfl_xor(s, 32);
    rinv[qt] = __builtin_amdgcn_rcpf(s);
  }
#pragma unroll
  for (int dt = 0; dt < 8; ++dt)
#pragma unroll
    for (int qt = 0; qt < 2; ++qt) {
      const int sg = i * 128 + w * 32 + qt * 16 + ln;
      const int d0 = h * 128 + dt * 16 + quad * 4;
      u16x4 ov;
#pragma unroll
      for (int r = 0; r < 4; ++r) ov[r] = f2bf(o_acc[dt][qt][r] * rinv[qt]);
      *(u16x4*)&ctx[((size_t)b << 22) + (size_t)sg * 2048 + d0] = ov;
    }
}

// ---------------- launch ----------------
extern "C" void kernel_launch(void* const* d_in, const int* in_sizes, int n_in,
                              void* d_out, int out_size, void* d_ws, size_t ws_size,
                              hipStream_t stream) {
  const float* x = (const float*)d_in[0];
  const float* Wq = (const float*)d_in[1];
  const float* bq = (const float*)d_in[2];
  const float* Wk = (const float*)d_in[3];
  const float* bk = (const float*)d_in[4];
  const float* Wv = (const float*)d_in[5];
  const float* bv = (const float*)d_in[6];
  const float* Wo = (const float*)d_in[7];
  const float* bo = (const float*)d_in[8];

  u16* ws = (u16*)d_ws;
  u16* xb = ws;
  u16* Wqb = xb + 8388608;
  u16* Wkb = Wqb + 4194304;
  u16* Wvb = Wkb + 4194304;
  u16* Wob = Wvb + 4194304;
  u16* Qb = Wob + 4194304;    // [B,H,S,D] (pre-scaled w/ log2e fold)
  u16* Kb = Qb + 8388608;     // [B,H,S,D]
  u16* Vtb = Kb + 8388608;    // [B,H,D,S]
  u16* ctxb = Vtb + 8388608;  // [B,S,E]

  cast6<<<dim3(4096, 6), 256, 0, stream>>>(x, Wq, Wk, Wv, Wo, ws);

  gemm_qk256<<<dim3(8, 16, 2), 512, 0, stream>>>(xb, Wqb, Wkb, bq, bk, Qb, Kb);
  gemm_v<<<dim3(16, 16), 512, 0, stream>>>(xb, Wvb, bv, Vtb);

  attn_kernel<<<dim3(16, 32), 256, 0, stream>>>(Qb, Kb, Vtb, ctxb);

  gemm_out<<<dim3(16, 16), 512, 0, stream>>>(ctxb, Wob, bo, (float*)d_out);
}